// Round 3
// baseline (2955.213 us; speedup 1.0000x reference)
//
#include <hip/hip_runtime.h>
#include <math.h>

#define B_ 32
#define T_ 20
#define H_ 256
#define F_ 512
#define NT_ 640

__device__ __forceinline__ float sigf(float x){ return 1.f/(1.f+__expf(-x)); }
__device__ __forceinline__ float lrelu(float x){ return x>0.f ? x : 0.2f*x; }
__device__ __forceinline__ float dot4(float4 a, float4 b){
  return fmaf(a.x,b.x, fmaf(a.y,b.y, fmaf(a.z,b.z, a.w*b.w)));
}

// Wc = w_ih + w_hh   (262144 floats, as float4)
__global__ void k_wc(const float* __restrict__ wih, const float* __restrict__ whh,
                     float* __restrict__ Wc){
  int i = blockIdx.x*256 + threadIdx.x;
  float4 a = ((const float4*)wih)[i];
  float4 b = ((const float4*)whh)[i];
  ((float4*)Wc)[i] = make_float4(a.x+b.x, a.y+b.y, a.z+b.z, a.w+b.w);
}

// bias1 = b_ih + b_hh ; bias0 = init_inp @ w_ih.T + bias1
__global__ void k_bias(const float* __restrict__ wih, const float* __restrict__ bih,
                       const float* __restrict__ bhh, const float* __restrict__ init_inp,
                       float* __restrict__ bias0, float* __restrict__ bias1){
  __shared__ __align__(16) float xs[H_];
  int tid = threadIdx.x;
  xs[tid] = init_inp[tid];
  __syncthreads();
  int j = blockIdx.x*256 + tid;
  const float4* wr = (const float4*)(wih + (size_t)j*H_);
  const float4* xx = (const float4*)xs;
  float acc = 0.f;
  #pragma unroll 8
  for(int k=0;k<H_/4;k++) acc += dot4(wr[k], xx[k]);
  float b1 = bih[j] + bhh[j];
  bias1[j] = b1;
  bias0[j] = acc + b1;
}

// out[b][j] = z[b] . W[j] + bias[j]   (h0 / c0)
__global__ void k_rowfc(const float* __restrict__ z, const float* __restrict__ W,
                        const float* __restrict__ bias, float* __restrict__ out){
  __shared__ __align__(16) float zs[H_];
  int b = blockIdx.x, j = threadIdx.x;
  zs[j] = z[b*H_ + j];
  __syncthreads();
  const float4* wr = (const float4*)(W + (size_t)j*H_);
  const float4* zz = (const float4*)zs;
  float acc = bias[j];
  #pragma unroll 8
  for(int k=0;k<H_/4;k++) acc += dot4(wr[k], zz[k]);
  out[b*H_+j] = acc;
}

__global__ void k_zero(float* p, int n){
  int i = blockIdx.x*256 + threadIdx.x;
  if(i<n) p[i]=0.f;
}

// one LSTM step: gates = hprev @ W.T + bias ; update c, write h
// grid (4 jgroups, 32 batch), block 256
__global__ void k_lstm(const float* __restrict__ hprev, float* __restrict__ c,
                       const float* __restrict__ W, const float* __restrict__ bias,
                       float* __restrict__ hout){
  __shared__ __align__(16) float hs[H_];
  __shared__ float gs[4][64];
  int b = blockIdx.y, jg = blockIdx.x, tid = threadIdx.x;
  hs[tid] = hprev[b*H_ + tid];
  __syncthreads();
  int g = tid>>6, jj = tid&63;
  int row = g*H_ + jg*64 + jj;
  const float4* wr = (const float4*)(W + (size_t)row*H_);
  const float4* hh = (const float4*)hs;
  float acc = bias[row];
  #pragma unroll 8
  for(int k=0;k<H_/4;k++) acc += dot4(wr[k], hh[k]);
  gs[g][jj] = acc;
  __syncthreads();
  if(tid < 64){
    int j = jg*64 + tid;
    float iv = gs[0][tid], fv = gs[1][tid], gv = gs[2][tid], ov = gs[3][tid];
    int ci = b*H_ + j;
    float cn = sigf(fv)*c[ci] + sigf(iv)*tanhf(gv);
    c[ci] = cn;
    hout[b*H_ + j] = sigf(ov)*tanhf(cn);
  }
}

// feats[n][f] = leaky(outs[t][b] . w[f] + bias[f]),  n = b*T+t. grid (2, 640)
__global__ void k_fcout(const float* __restrict__ outs, const float* __restrict__ w,
                        const float* __restrict__ bias, float* __restrict__ feats){
  __shared__ __align__(16) float hs[H_];
  int n = blockIdx.y; int b = n/T_, t = n - b*T_;
  int tid = threadIdx.x;
  hs[tid] = outs[(t*B_ + b)*H_ + tid];
  __syncthreads();
  int f = blockIdx.x*256 + tid;
  const float4* wr = (const float4*)(w + (size_t)f*H_);
  const float4* hh = (const float4*)hs;
  float acc = bias[f];
  #pragma unroll 8
  for(int k=0;k<H_/4;k++) acc += dot4(wr[k], hh[k]);
  feats[n*F_ + f] = lrelu(acc);
}

// fc1[n][oc] = leaky(feats[n] . w[oc] + b[oc]); block: 256 thr, 4 oc-rows x 8 n
// grid (4 ocg, 80 ngroups)
__global__ __launch_bounds__(256) void k_cnnfc(const float* __restrict__ feats,
    const float* __restrict__ w, const float* __restrict__ bias, float* __restrict__ out){
  __shared__ __align__(16) float fe[8*F_];
  int ocg = blockIdx.x, ng = blockIdx.y, tid = threadIdx.x;
  const float4* src = (const float4*)(feats + (size_t)ng*8*F_);
  float4* dst = (float4*)fe;
  for(int i=tid;i<8*F_/4;i+=256) dst[i] = src[i];
  __syncthreads();
  int oc0 = ocg*1024 + tid;
  const float4* w0 = (const float4*)(w + (size_t)(oc0      )*F_);
  const float4* w1 = (const float4*)(w + (size_t)(oc0+256 )*F_);
  const float4* w2 = (const float4*)(w + (size_t)(oc0+512 )*F_);
  const float4* w3 = (const float4*)(w + (size_t)(oc0+768 )*F_);
  float acc[4][8];
  #pragma unroll
  for(int i=0;i<4;i++){
    float bv = bias[oc0 + i*256];
    #pragma unroll
    for(int nn=0;nn<8;nn++) acc[i][nn]=bv;
  }
  for(int k=0;k<F_/4;k++){
    float4 wv0=w0[k], wv1=w1[k], wv2=w2[k], wv3=w3[k];
    #pragma unroll
    for(int nn=0;nn<8;nn++){
      float4 f = ((const float4*)(fe + nn*F_))[k];
      acc[0][nn] += dot4(wv0,f);
      acc[1][nn] += dot4(wv1,f);
      acc[2][nn] += dot4(wv2,f);
      acc[3][nn] += dot4(wv3,f);
    }
  }
  #pragma unroll
  for(int i=0;i<4;i++)
    #pragma unroll
    for(int nn=0;nn<8;nn++)
      out[(size_t)(ng*8+nn)*4096 + ocg*1024 + i*256 + tid] = lrelu(acc[i][nn]);
}

// ---------------------------------------------------------------------------
// deconv2-style (batched full-image LDS), used for layer 0 (4x4 input).
template<int IC, int OC, int IH, int NB, int Tt, int Lg, int Ko>
__global__ __launch_bounds__(256,4) void k_deconv2(const float* __restrict__ in,
    const float* __restrict__ w, float* __restrict__ out,
    float* __restrict__ ssum, float* __restrict__ ssq){
  static_assert(Tt*Lg == 256, "block mismatch");
  constexpr int IW = IH, OW = 2*IH;
  constexpr int S = IH*IW;
  constexpr int OCG = OC/(Lg*Ko);
  __shared__ float lin[NB*IC*S];

  int bx = blockIdx.x;
  int os = bx % OCG, ts = bx / OCG;
  int n0 = blockIdx.y*NB;
  int tid = threadIdx.x;

  {
    const float4* src = (const float4*)(in + (size_t)n0*IC*S);
    float4* dst = (float4*)lin;
    constexpr int NV = NB*IC*S/4;
    #pragma unroll
    for(int i=0;i<NV/256;i++) dst[tid + i*256] = src[tid + i*256];
  }
  __syncthreads();

  int lg = tid / Tt, t = tid % Tt;
  int tile = ts*Tt + t;
  int ty = tile / IW, tx = tile % IW;
  int oc0 = os*(Lg*Ko) + lg*Ko;

  int offs[3][3]; float msk[3][3];
  #pragma unroll
  for(int dy=0;dy<3;dy++){
    int iy = ty-1+dy; bool vy = (iy>=0)&&(iy<IH);
    #pragma unroll
    for(int dx=0;dx<3;dx++){
      int ix = tx-1+dx; bool vx = (ix>=0)&&(ix<IW);
      offs[dy][dx] = (vy&&vx) ? (iy*IW+ix) : 0;
      msk[dy][dx]  = (vy&&vx) ? 1.f : 0.f;
    }
  }

  float acc[Ko][NB][2][2];
  #pragma unroll
  for(int ko=0;ko<Ko;ko++)
    #pragma unroll
    for(int nb=0;nb<NB;nb++)
      #pragma unroll
      for(int r=0;r<2;r++){ acc[ko][nb][r][0]=0.f; acc[ko][nb][r][1]=0.f; }

  for(int ic=0; ic<IC; ic++){
    float v[NB][3][3];
    #pragma unroll
    for(int nb=0;nb<NB;nb++){
      const float* p = lin + (nb*IC + ic)*S;
      #pragma unroll
      for(int dy=0;dy<3;dy++)
        #pragma unroll
        for(int dx=0;dx<3;dx++)
          v[nb][dy][dx] = p[offs[dy][dx]] * msk[dy][dx];
    }
    const float4* wr = (const float4*)(w + ((size_t)ic*OC + oc0)*16);
    #pragma unroll
    for(int ko=0;ko<Ko;ko++){
      float4 w0=wr[ko*4+0], w1=wr[ko*4+1], w2=wr[ko*4+2], w3=wr[ko*4+3];
      float wv[16] = {w0.x,w0.y,w0.z,w0.w, w1.x,w1.y,w1.z,w1.w,
                      w2.x,w2.y,w2.z,w2.w, w3.x,w3.y,w3.z,w3.w};
      #pragma unroll
      for(int nb=0;nb<NB;nb++)
        #pragma unroll
        for(int r=0;r<2;r++)
          #pragma unroll
          for(int s2=0;s2<2;s2++)
            #pragma unroll
            for(int a=0;a<2;a++)
              #pragma unroll
              for(int b2=0;b2<2;b2++)
                acc[ko][nb][r][s2] = fmaf(v[nb][a+r][b2+s2], wv[(3-2*a-r)*4 + (3-2*b2-s2)], acc[ko][nb][r][s2]);
    }
  }

  constexpr int RW = (Tt<64)?Tt:64;
  #pragma unroll
  for(int ko=0;ko<Ko;ko++){
    float s_=0.f, q_=0.f;
    #pragma unroll
    for(int nb=0;nb<NB;nb++){
      float* ob = out + ((size_t)(n0+nb)*OC + oc0+ko)*4*S;
      #pragma unroll
      for(int r=0;r<2;r++)
        #pragma unroll
        for(int s2=0;s2<2;s2++){
          float vv = acc[ko][nb][r][s2];
          ob[(2*ty+r)*OW + (2*tx+s2)] = vv;
          s_ += vv; q_ = fmaf(vv,vv,q_);
        }
    }
    #pragma unroll
    for(int m=1;m<RW;m<<=1){ s_ += __shfl_xor(s_,m,RW); q_ += __shfl_xor(q_,m,RW); }
    if((t & (RW-1))==0){ atomicAdd(&ssum[oc0+ko], s_); atomicAdd(&ssq[oc0+ko], q_); }
  }
}

// ---------------------------------------------------------------------------
// v3 deconv: row-sliced LDS staging. Block owns RB input rows x all cols,
// stages RB+2 rows (clamped; msk zeroes borders). Lg lanegroups x Ko oc.
// grid.x = OCG*TS, grid.y = 640.
template<int IC, int OC, int IH, int RB, int Lg, int Ko>
__global__ __launch_bounds__(256,4) void k_deconv3(const float* __restrict__ in,
    const float* __restrict__ w, float* __restrict__ out,
    float* __restrict__ ssum, float* __restrict__ ssq){
  constexpr int IW = IH, OW = 2*IH;
  constexpr int S = IH*IW;
  constexpr int Tt = RB*IW;
  static_assert(Tt*Lg == 256, "block mismatch");
  constexpr int SR = RB+2;
  constexpr int OCG = OC/(Lg*Ko);
  constexpr int TS = IH/RB;
  constexpr int IW4 = IW/4;
  __shared__ float lin[IC*SR*IW];

  int bx = blockIdx.x;
  int os = bx % OCG, rg = bx / OCG;
  int n = blockIdx.y;
  int tid = threadIdx.x;

  // stage SR rows (clamped) of all IC channels: lin[ic][j][col]
  {
    const float4* src = (const float4*)in;
    float4* dst = (float4*)lin;
    constexpr int NV4 = IC*SR*IW4;
    static_assert(NV4 % 256 == 0, "stage divisibility");
    #pragma unroll
    for(int i=0;i<NV4/256;i++){
      int idx = tid + i*256;
      int ic = idx/(SR*IW4); int rem = idx - ic*(SR*IW4);
      int j = rem/IW4; int c4 = rem - j*IW4;
      int gr = RB*rg - 1 + j;
      gr = gr < 0 ? 0 : (gr > IH-1 ? IH-1 : gr);
      dst[idx] = src[((size_t)(n*IC+ic)*IH + gr)*IW4 + c4];
    }
  }
  __syncthreads();

  int lg = tid / Tt, t = tid % Tt;
  int tl = t / IW, tx = t % IW;
  int ty = RB*rg + tl;
  int oc0 = os*(Lg*Ko) + lg*Ko;

  int offs[3][3]; float msk[3][3];
  #pragma unroll
  for(int dy=0;dy<3;dy++){
    int iy = ty-1+dy; bool vy = (iy>=0)&&(iy<IH);
    #pragma unroll
    for(int dx=0;dx<3;dx++){
      int ix = tx-1+dx; bool vx = (ix>=0)&&(ix<IW);
      int lcol = ix < 0 ? 0 : (ix > IW-1 ? IW-1 : ix);
      offs[dy][dx] = (tl+dy)*IW + lcol;
      msk[dy][dx]  = (vy&&vx) ? 1.f : 0.f;
    }
  }

  float acc[Ko][2][2];
  #pragma unroll
  for(int ko=0;ko<Ko;ko++)
    #pragma unroll
    for(int r=0;r<2;r++){ acc[ko][r][0]=0.f; acc[ko][r][1]=0.f; }

  #pragma unroll 2
  for(int ic=0; ic<IC; ic++){
    const float* p = lin + ic*(SR*IW);
    float v[3][3];
    #pragma unroll
    for(int dy=0;dy<3;dy++)
      #pragma unroll
      for(int dx=0;dx<3;dx++)
        v[dy][dx] = p[offs[dy][dx]] * msk[dy][dx];
    const float4* wr = (const float4*)(w + ((size_t)ic*OC + oc0)*16);
    #pragma unroll
    for(int ko=0;ko<Ko;ko++){
      float4 w0=wr[ko*4+0], w1=wr[ko*4+1], w2=wr[ko*4+2], w3=wr[ko*4+3];
      float wv[16] = {w0.x,w0.y,w0.z,w0.w, w1.x,w1.y,w1.z,w1.w,
                      w2.x,w2.y,w2.z,w2.w, w3.x,w3.y,w3.z,w3.w};
      #pragma unroll
      for(int r=0;r<2;r++)
        #pragma unroll
        for(int s2=0;s2<2;s2++)
          #pragma unroll
          for(int a=0;a<2;a++)
            #pragma unroll
            for(int b2=0;b2<2;b2++)
              acc[ko][r][s2] = fmaf(v[a+r][b2+s2], wv[(3-2*a-r)*4 + (3-2*b2-s2)], acc[ko][r][s2]);
    }
  }

  #pragma unroll
  for(int ko=0;ko<Ko;ko++){
    float s_=0.f, q_=0.f;
    float* ob = out + ((size_t)n*OC + oc0+ko)*4*S;
    #pragma unroll
    for(int r=0;r<2;r++)
      #pragma unroll
      for(int s2=0;s2<2;s2++){
        float vv = acc[ko][r][s2];
        ob[(2*ty+r)*OW + (2*tx+s2)] = vv;
        s_ += vv; q_ = fmaf(vv,vv,q_);
      }
    #pragma unroll
    for(int m=1;m<64;m<<=1){ s_ += __shfl_xor(s_,m,64); q_ += __shfl_xor(q_,m,64); }
    if((t & 63)==0){ atomicAdd(&ssum[oc0+ko], s_); atomicAdd(&ssq[oc0+ko], q_); }
  }
}

// ---------------------------------------------------------------------------
// final ConvTranspose (32->1) + sigmoid. Row-sliced staging + weights in LDS.
// Block: 256 thr = 8 rows x 32 cols. grid(4, 640).
__global__ __launch_bounds__(256,3) void k_final(const float* __restrict__ in,
    const float* __restrict__ w, float* __restrict__ dout, const float* __restrict__ fb){
  constexpr int IC = 32, IH = 32, IW = 32, OW = 64, RB = 8, SR = RB+2;
  __shared__ float lin[IC*SR*IW];   // 40 KB
  __shared__ __align__(16) float lw[IC*16]; // 2 KB

  int rg = blockIdx.x;
  int n = blockIdx.y;
  int tid = threadIdx.x;

  {
    const float4* src = (const float4*)in;
    float4* dst = (float4*)lin;
    constexpr int NV4 = IC*SR*IW/4;   // 2560
    #pragma unroll
    for(int i=0;i<NV4/256;i++){
      int idx = tid + i*256;
      int ic = idx/(SR*8); int rem = idx - ic*(SR*8);
      int j = rem/8; int c4 = rem - j*8;
      int gr = RB*rg - 1 + j;
      gr = gr < 0 ? 0 : (gr > IH-1 ? IH-1 : gr);
      dst[idx] = src[((size_t)(n*IC+ic)*IH + gr)*8 + c4];
    }
    if(tid < 128) ((float4*)lw)[tid] = ((const float4*)w)[tid];
  }
  float fbv = fb[0];
  __syncthreads();

  int tl = tid / IW, tx = tid % IW;
  int ty = RB*rg + tl;

  int offs[3][3]; float msk[3][3];
  #pragma unroll
  for(int dy=0;dy<3;dy++){
    int iy = ty-1+dy; bool vy = (iy>=0)&&(iy<IH);
    #pragma unroll
    for(int dx=0;dx<3;dx++){
      int ix = tx-1+dx; bool vx = (ix>=0)&&(ix<IW);
      int lcol = ix < 0 ? 0 : (ix > IW-1 ? IW-1 : ix);
      offs[dy][dx] = (tl+dy)*IW + lcol;
      msk[dy][dx]  = (vy&&vx) ? 1.f : 0.f;
    }
  }

  float acc[2][2] = {{0.f,0.f},{0.f,0.f}};
  #pragma unroll 4
  for(int ic=0; ic<IC; ic++){
    const float* p = lin + ic*(SR*IW);
    float v[3][3];
    #pragma unroll
    for(int dy=0;dy<3;dy++)
      #pragma unroll
      for(int dx=0;dx<3;dx++)
        v[dy][dx] = p[offs[dy][dx]] * msk[dy][dx];
    const float4* wr = (const float4*)(lw + ic*16);
    float4 w0=wr[0], w1=wr[1], w2=wr[2], w3=wr[3];
    float wv[16] = {w0.x,w0.y,w0.z,w0.w, w1.x,w1.y,w1.z,w1.w,
                    w2.x,w2.y,w2.z,w2.w, w3.x,w3.y,w3.z,w3.w};
    #pragma unroll
    for(int r=0;r<2;r++)
      #pragma unroll
      for(int s2=0;s2<2;s2++)
        #pragma unroll
        for(int a=0;a<2;a++)
          #pragma unroll
          for(int b2=0;b2<2;b2++)
            acc[r][s2] = fmaf(v[a+r][b2+s2], wv[(3-2*a-r)*4 + (3-2*b2-s2)], acc[r][s2]);
  }

  float* ob = dout + (size_t)n*OW*OW;
  #pragma unroll
  for(int r=0;r<2;r++)
    #pragma unroll
    for(int s2=0;s2<2;s2++){
      float vv = acc[r][s2] + fbv;
      ob[(2*ty+r)*OW + (2*tx+s2)] = 1.f/(1.f+__expf(-vv));
    }
}

// in-place BN(training stats) + leaky, float4-vectorized. x layout (N, OC, SP)
template<int OC, int SP>
__global__ void k_bn(float* __restrict__ x, const float* __restrict__ ssum,
                     const float* __restrict__ ssq, const float* __restrict__ g,
                     const float* __restrict__ be, int n4){
  int i = blockIdx.x*256 + threadIdx.x;
  if(i >= n4) return;
  int c = ((i*4)/SP) % OC;
  const float inv_cnt = 1.f/(640.f*SP);
  float m = ssum[c]*inv_cnt;
  float var = ssq[c]*inv_cnt - m*m;
  float sc = g[c]*rsqrtf(var + 1e-5f);
  float sh = be[c] - m*sc;
  float4 xv = ((float4*)x)[i];
  xv.x = lrelu(fmaf(xv.x, sc, sh));
  xv.y = lrelu(fmaf(xv.y, sc, sh));
  xv.z = lrelu(fmaf(xv.z, sc, sh));
  xv.w = lrelu(fmaf(xv.w, sc, sh));
  ((float4*)x)[i] = xv;
}

extern "C" void kernel_launch(void* const* d_in, const int* in_sizes, int n_in,
                              void* d_out, int out_size, void* d_ws, size_t ws_size,
                              hipStream_t stream){
  const float* z       = (const float*)d_in[0];
  const float* fhw     = (const float*)d_in[1];
  const float* fhb     = (const float*)d_in[2];
  const float* fcw     = (const float*)d_in[3];
  const float* fcb     = (const float*)d_in[4];
  const float* wih     = (const float*)d_in[5];
  const float* bih     = (const float*)d_in[6];
  const float* whh     = (const float*)d_in[7];
  const float* bhh     = (const float*)d_in[8];
  const float* init_inp= (const float*)d_in[9];
  const float* fow     = (const float*)d_in[10];
  const float* fob     = (const float*)d_in[11];
  const float* cfw     = (const float*)d_in[12];
  const float* cfb     = (const float*)d_in[13];
  const float* dw0     = (const float*)d_in[14];
  const float* g0      = (const float*)d_in[15];
  const float* be0     = (const float*)d_in[16];
  const float* dw1     = (const float*)d_in[17];
  const float* g1      = (const float*)d_in[18];
  const float* be1     = (const float*)d_in[19];
  const float* dw2     = (const float*)d_in[20];
  const float* g2      = (const float*)d_in[21];
  const float* be2     = (const float*)d_in[22];
  const float* fw      = (const float*)d_in[23];
  const float* fb      = (const float*)d_in[24];

  float* ws    = (float*)d_ws;
  float* conv2 = ws;                 // 640*32*1024 = 20971520
  float* conv1 = ws + 20971520;      // 640*64*256  = 10485760
  float* conv0 = ws + 31457280;      // 640*128*64  =  5242880
  float* fc1   = ws + 36700160;      // 640*4096    =  2621440
  float* feats = ws + 39321600;      // 640*512     =   327680
  float* outs  = ws + 39649280;      // 20*32*256   =   163840
  float* Wc    = ws + 39813120;      // 1024*256    =   262144
  float* bias0 = ws + 40075264;      // 1024
  float* bias1 = ws + 40076288;      // 1024
  float* h0    = ws + 40077312;      // 8192
  float* cbuf  = ws + 40085504;      // 8192
  float* stats = ws + 40093696;      // 448
  float* sum0 = stats,     *sq0 = stats+128;
  float* sum1 = stats+256, *sq1 = stats+320;
  float* sum2 = stats+384, *sq2 = stats+416;

  hipLaunchKernelGGL(k_wc,    dim3(256), dim3(256), 0, stream, wih, whh, Wc);
  hipLaunchKernelGGL(k_bias,  dim3(4),   dim3(256), 0, stream, wih, bih, bhh, init_inp, bias0, bias1);
  hipLaunchKernelGGL(k_rowfc, dim3(32),  dim3(256), 0, stream, z, fhw, fhb, h0);
  hipLaunchKernelGGL(k_rowfc, dim3(32),  dim3(256), 0, stream, z, fcw, fcb, cbuf);
  hipLaunchKernelGGL(k_zero,  dim3(2),   dim3(256), 0, stream, stats, 448);

  for(int t=0;t<T_;t++){
    const float* W  = (t==0) ? whh   : Wc;
    const float* bs = (t==0) ? bias0 : bias1;
    const float* hp = (t==0) ? h0    : outs + (t-1)*B_*H_;
    hipLaunchKernelGGL(k_lstm, dim3(4,32), dim3(256), 0, stream, hp, cbuf, W, bs, outs + t*B_*H_);
  }

  hipLaunchKernelGGL(k_fcout, dim3(2,NT_), dim3(256), 0, stream, outs, fow, fob, feats);
  hipLaunchKernelGGL(k_cnnfc, dim3(4,80),  dim3(256), 0, stream, feats, cfw, cfb, fc1);

  // deconv0: IC=256 OC=128 IH=4 | NB=2 Tt=16 Lg=16 Ko=2 -> OCG=4, grid(4,320)
  hipLaunchKernelGGL((k_deconv2<256,128,4,2,16,16,2>), dim3(4,320), dim3(256), 0, stream,
                     fc1, dw0, conv0, sum0, sq0);
  hipLaunchKernelGGL((k_bn<128,64>),   dim3(5120),  dim3(256), 0, stream, conv0, sum0, sq0, g0, be0, 1310720);
  // deconv1: IC=128 OC=64 IH=8 | RB=8 Lg=4 Ko=8 -> OCG=2, TS=1, grid(2,640)
  hipLaunchKernelGGL((k_deconv3<128,64,8,8,4,8>), dim3(2,640), dim3(256), 0, stream,
                     conv0, dw1, conv1, sum1, sq1);
  hipLaunchKernelGGL((k_bn<64,256>),   dim3(10240), dim3(256), 0, stream, conv1, sum1, sq1, g1, be1, 2621440);
  // deconv2: IC=64 OC=32 IH=16 | RB=4 Lg=4 Ko=8 -> OCG=1, TS=4, grid(4,640)
  hipLaunchKernelGGL((k_deconv3<64,32,16,4,4,8>), dim3(4,640), dim3(256), 0, stream,
                     conv1, dw2, conv2, sum2, sq2);
  hipLaunchKernelGGL((k_bn<32,1024>),  dim3(20480), dim3(256), 0, stream, conv2, sum2, sq2, g2, be2, 5242880);
  // final: IC=32 OC=1, 32x32 -> 64x64, grid(4,640)
  hipLaunchKernelGGL(k_final, dim3(4,640), dim3(256), 0, stream, conv2, fw, (float*)d_out, fb);
}

// Round 7
// 1989.064 us; speedup vs baseline: 1.4857x; 1.4857x over previous
//
#include <hip/hip_runtime.h>
#include <math.h>

#define B_ 32
#define T_ 20
#define H_ 256
#define F_ 512
#define NT_ 640

typedef __attribute__((ext_vector_type(8))) _Float16 half8v;
typedef __attribute__((ext_vector_type(4))) float f32x4;

__device__ __forceinline__ float sigf(float x){ return 1.f/(1.f+__expf(-x)); }
__device__ __forceinline__ float lrelu(float x){ return x>0.f ? x : 0.2f*x; }
__device__ __forceinline__ float dot4(float4 a, float4 b){
  return fmaf(a.x,b.x, fmaf(a.y,b.y, fmaf(a.z,b.z, a.w*b.w)));
}
__device__ __forceinline__ unsigned short f16bits(float x){
  _Float16 h = (_Float16)x;                 // RNE
  union { _Float16 h; unsigned short u; } cv; cv.h = h; return cv.u;
}

// Wc = w_ih + w_hh
__global__ void k_wc(const float* __restrict__ wih, const float* __restrict__ whh,
                     float* __restrict__ Wc){
  int i = blockIdx.x*256 + threadIdx.x;
  float4 a = ((const float4*)wih)[i];
  float4 b = ((const float4*)whh)[i];
  ((float4*)Wc)[i] = make_float4(a.x+b.x, a.y+b.y, a.z+b.z, a.w+b.w);
}

// bias1 = b_ih + b_hh ; bias0 = init_inp @ w_ih.T + bias1
__global__ void k_bias(const float* __restrict__ wih, const float* __restrict__ bih,
                       const float* __restrict__ bhh, const float* __restrict__ init_inp,
                       float* __restrict__ bias0, float* __restrict__ bias1){
  __shared__ __align__(16) float xs[H_];
  int tid = threadIdx.x;
  xs[tid] = init_inp[tid];
  __syncthreads();
  int j = blockIdx.x*256 + tid;
  const float4* wr = (const float4*)(wih + (size_t)j*H_);
  const float4* xx = (const float4*)xs;
  float acc = 0.f;
  #pragma unroll 8
  for(int k=0;k<H_/4;k++) acc += dot4(wr[k], xx[k]);
  float b1 = bih[j] + bhh[j];
  bias1[j] = b1;
  bias0[j] = acc + b1;
}

// out[b][j] = z[b] . W[j] + bias[j]
__global__ void k_rowfc(const float* __restrict__ z, const float* __restrict__ W,
                        const float* __restrict__ bias, float* __restrict__ out){
  __shared__ __align__(16) float zs[H_];
  int b = blockIdx.x, j = threadIdx.x;
  zs[j] = z[b*H_ + j];
  __syncthreads();
  const float4* wr = (const float4*)(W + (size_t)j*H_);
  const float4* zz = (const float4*)zs;
  float acc = bias[j];
  #pragma unroll 8
  for(int k=0;k<H_/4;k++) acc += dot4(wr[k], zz[k]);
  out[b*H_+j] = acc;
}

__global__ void k_zero(float* p, int n){
  int i = blockIdx.x*256 + threadIdx.x;
  if(i<n) p[i]=0.f;
}

// one LSTM step
__global__ void k_lstm(const float* __restrict__ hprev, float* __restrict__ c,
                       const float* __restrict__ W, const float* __restrict__ bias,
                       float* __restrict__ hout){
  __shared__ __align__(16) float hs[H_];
  __shared__ float gs[4][64];
  int b = blockIdx.y, jg = blockIdx.x, tid = threadIdx.x;
  hs[tid] = hprev[b*H_ + tid];
  __syncthreads();
  int g = tid>>6, jj = tid&63;
  int row = g*H_ + jg*64 + jj;
  const float4* wr = (const float4*)(W + (size_t)row*H_);
  const float4* hh = (const float4*)hs;
  float acc = bias[row];
  #pragma unroll 8
  for(int k=0;k<H_/4;k++) acc += dot4(wr[k], hh[k]);
  gs[g][jj] = acc;
  __syncthreads();
  if(tid < 64){
    int j = jg*64 + tid;
    float iv = gs[0][tid], fv = gs[1][tid], gv = gs[2][tid], ov = gs[3][tid];
    int ci = b*H_ + j;
    float cn = sigf(fv)*c[ci] + sigf(iv)*tanhf(gv);
    c[ci] = cn;
    hout[b*H_ + j] = sigf(ov)*tanhf(cn);
  }
}

// feats[n][f] = leaky(outs[t][b] . w[f] + bias[f]),  n = b*T+t
__global__ void k_fcout(const float* __restrict__ outs, const float* __restrict__ w,
                        const float* __restrict__ bias, float* __restrict__ feats){
  __shared__ __align__(16) float hs[H_];
  int n = blockIdx.y; int b = n/T_, t = n - b*T_;
  int tid = threadIdx.x;
  hs[tid] = outs[(t*B_ + b)*H_ + tid];
  __syncthreads();
  int f = blockIdx.x*256 + tid;
  const float4* wr = (const float4*)(w + (size_t)f*H_);
  const float4* hh = (const float4*)hs;
  float acc = bias[f];
  #pragma unroll 8
  for(int k=0;k<H_/4;k++) acc += dot4(wr[k], hh[k]);
  feats[n*F_ + f] = lrelu(acc);
}

// fc1[n][oc] = leaky(feats[n] . w[oc] + b[oc])
__global__ __launch_bounds__(256) void k_cnnfc(const float* __restrict__ feats,
    const float* __restrict__ w, const float* __restrict__ bias, float* __restrict__ out){
  __shared__ __align__(16) float fe[8*F_];
  int ocg = blockIdx.x, ng = blockIdx.y, tid = threadIdx.x;
  const float4* src = (const float4*)(feats + (size_t)ng*8*F_);
  float4* dst = (float4*)fe;
  for(int i=tid;i<8*F_/4;i+=256) dst[i] = src[i];
  __syncthreads();
  int oc0 = ocg*1024 + tid;
  const float4* w0 = (const float4*)(w + (size_t)(oc0      )*F_);
  const float4* w1 = (const float4*)(w + (size_t)(oc0+256 )*F_);
  const float4* w2 = (const float4*)(w + (size_t)(oc0+512 )*F_);
  const float4* w3 = (const float4*)(w + (size_t)(oc0+768 )*F_);
  float acc[4][8];
  #pragma unroll
  for(int i=0;i<4;i++){
    float bv = bias[oc0 + i*256];
    #pragma unroll
    for(int nn=0;nn<8;nn++) acc[i][nn]=bv;
  }
  for(int k=0;k<F_/4;k++){
    float4 wv0=w0[k], wv1=w1[k], wv2=w2[k], wv3=w3[k];
    #pragma unroll
    for(int nn=0;nn<8;nn++){
      float4 f = ((const float4*)(fe + nn*F_))[k];
      acc[0][nn] += dot4(wv0,f);
      acc[1][nn] += dot4(wv1,f);
      acc[2][nn] += dot4(wv2,f);
      acc[3][nn] += dot4(wv3,f);
    }
  }
  #pragma unroll
  for(int i=0;i<4;i++)
    #pragma unroll
    for(int nn=0;nn<8;nn++)
      out[(size_t)(ng*8+nn)*4096 + ocg*1024 + i*256 + tid] = lrelu(acc[i][nn]);
}

// ---------------------------------------------------------------------------
// weight transform: Wz[n=(oc*4+py*2+px)][k=(dy3*3+dx3)*IC+ic] (fp16, k-fastest)
template<int IC, int OC>
__global__ void k_wz(const float* __restrict__ w, unsigned short* __restrict__ Wz){
  constexpr int K9 = 9*IC, N4 = 4*OC;
  int i = blockIdx.x*256 + threadIdx.x;
  if(i >= N4*K9) return;
  int n = i / K9; int k = i - n*K9;
  int oc = n>>2, py = (n>>1)&1, px = n&1;
  int dd = k / IC; int ic = k - dd*IC;
  int dy3 = dd/3, dx3 = dd - 3*dy3;
  int ky = py + 3 - 2*dy3, kx = px + 3 - 2*dx3;
  float v = 0.f;
  if(ky>=0 && ky<4 && kx>=0 && kx<4)
    v = w[(((size_t)ic*OC + oc)*4 + ky)*4 + kx];
  Wz[i] = f16bits(v);
}

// ---------------------------------------------------------------------------
// MFMA implicit-GEMM deconv, SPLIT-fp16 activations (A = hi + lo, fp32-exact).
// PLAIN staging (no fused BN this round — bisect).
template<int IC, int OC, int IH, int NL, int RB, int SR, int BM, bool BNIN>
__global__ __launch_bounds__(256) void k_gemmdc(
    const float* __restrict__ in, const unsigned short* __restrict__ Wz,
    float* __restrict__ out, const float* __restrict__ sc, const float* __restrict__ sh,
    float* __restrict__ ssum, float* __restrict__ ssq)
{
  constexpr int IW = IH, OW = 2*IH;
  constexpr int S  = IH*IW, S4 = 4*S;
  constexpr int K9 = 9*IC;
  constexpr int ICp = IC + 8;
  constexpr int TS = IH/RB;
  constexpr int P  = NL*SR*IW;
  constexpr int NK = K9/32;
  constexpr int BN = 128;
  constexpr int AM = BM/32;
  static_assert(NL*RB*IW == BM, "BM mismatch");

  __shared__ unsigned short linH[P*ICp];
  __shared__ unsigned short linL[P*ICp];
  __shared__ unsigned short bt[BN*32];

  const int tid = threadIdx.x;
  const int bm = blockIdx.x, bn0 = blockIdx.y*BN;
  const int nimg0 = (bm/TS)*NL;
  const int rg = bm % TS;
  const int W0 = (SR==IH) ? 0 : (rg*RB - 1);

  {
    constexpr int NIT = P*(IC/8)/256;
    #pragma unroll
    for(int it=0; it<NIT; ++it){
      int i = tid + it*256;
      int p = i % P; int icb = (i/P)*8;
      int x = p % IW; int t1 = p/IW; int j = t1 % SR; int nl = t1/SR;
      int gr = W0 + j;
      bool ok = (gr>=0) && (gr<IH);
      const float* src = in + ((size_t)(nimg0+nl)*IC + icb)*S + gr*IW + x;
      unsigned short hh[8], ll[8];
      #pragma unroll
      for(int e=0;e<8;e++){
        float v = ok ? src[(size_t)e*S] : 0.f;
        if(BNIN) v = lrelu(fmaf(v, sc[icb+e], sh[icb+e]));
        _Float16 hi = (_Float16)v;
        float lo = v - (float)hi;
        union { _Float16 h; unsigned short u; } c1, c2;
        c1.h = hi; c2.h = (_Float16)lo;
        hh[e] = c1.u; ll[e] = c2.u;
      }
      *(uint4*)&linH[p*ICp + icb] = *(uint4*)hh;
      *(uint4*)&linL[p*ICp + icb] = *(uint4*)ll;
    }
  }

  const int lane = tid & 63, wvi = tid>>6;
  const int wm = wvi>>1, wn = wvi&1;
  const int l15 = lane & 15, lh = lane>>4;

  int mxA[AM], mylA[AM], nlA[AM];
  #pragma unroll
  for(int a=0;a<AM;a++){
    int r = wm*(BM/2) + a*16 + l15;
    mxA[a] = r % IW; int t = r/IW; mylA[a] = t % RB; nlA[a] = t/RB;
  }

  f32x4 acc[AM][4] = {};

  for(int ks=0; ks<NK; ++ks){
    __syncthreads();
    #pragma unroll
    for(int q=0;q<2;q++){
      int idx = tid + q*256;
      int n = idx>>2, h = idx&3;
      const uint4* s4p = (const uint4*)(Wz + (size_t)(bn0+n)*K9 + ks*32 + h*8);
      *(uint4*)&bt[n*32 + h*8] = *s4p;
    }
    __syncthreads();

    int k0 = ks*32;
    int dd = k0 / IC; int icb = k0 - dd*IC;
    int dy3 = dd/3, dx3 = dd - 3*dy3;

    half8v AfH[AM], AfL[AM], Bf[4];
    #pragma unroll
    for(int a=0;a<AM;a++){
      int gx = mxA[a] - 1 + dx3;
      bool vx = (gx>=0) && (gx<IW);
      int gxc = gx<0 ? 0 : (gx>IW-1 ? IW-1 : gx);
      int jyc; bool vy;
      if(SR==IH){
        int jy = mylA[a] - 1 + dy3;
        vy = (jy>=0) && (jy<IH);
        jyc = jy<0 ? 0 : (jy>SR-1 ? SR-1 : jy);
      } else {
        jyc = mylA[a] + dy3; vy = true;
      }
      int p = (nlA[a]*SR + jyc)*IW + gxc;
      half8v fH = *(const half8v*)&linH[p*ICp + icb + lh*8];
      half8v fL = *(const half8v*)&linL[p*ICp + icb + lh*8];
      if(!(vx&&vy)){
        #pragma unroll
        for(int e=0;e<8;e++){ fH[e] = (_Float16)0.f; fL[e] = (_Float16)0.f; }
      }
      AfH[a] = fH; AfL[a] = fL;
    }
    #pragma unroll
    for(int b=0;b<4;b++)
      Bf[b] = *(const half8v*)&bt[(wn*64 + b*16 + l15)*32 + lh*8];

    #pragma unroll
    for(int a=0;a<AM;a++)
      #pragma unroll
      for(int b=0;b<4;b++){
        acc[a][b] = __builtin_amdgcn_mfma_f32_16x16x32_f16(AfH[a], Bf[b], acc[a][b], 0, 0, 0);
        acc[a][b] = __builtin_amdgcn_mfma_f32_16x16x32_f16(AfL[a], Bf[b], acc[a][b], 0, 0, 0);
      }
  }

  float sb[4] = {0,0,0,0}, qb[4] = {0,0,0,0};
  #pragma unroll
  for(int b=0;b<4;b++){
    int nidx = bn0 + wn*64 + b*16 + l15;
    int oc = nidx>>2, py = (nidx>>1)&1, px = nidx&1;
    #pragma unroll
    for(int a=0;a<AM;a++){
      f32x4 c = acc[a][b];
      #pragma unroll
      for(int r=0;r<4;r++){
        int rr = wm*(BM/2) + a*16 + lh*4 + r;
        int mx = rr % IW; int t = rr/IW; int myl = t % RB; int nl = t/RB;
        int myg = (SR==IH) ? myl : (rg*RB + myl);
        float v = c[r];
        out[((size_t)(nimg0+nl)*OC + oc)*S4 + (size_t)(2*myg+py)*OW + (2*mx+px)] = v;
        sb[b] += v; qb[b] = fmaf(v,v,qb[b]);
      }
    }
  }
  #pragma unroll
  for(int b=0;b<4;b++){
    float s_ = sb[b], q_ = qb[b];
    s_ += __shfl_xor(s_,1);  q_ += __shfl_xor(q_,1);
    s_ += __shfl_xor(s_,2);  q_ += __shfl_xor(q_,2);
    s_ += __shfl_xor(s_,16); q_ += __shfl_xor(q_,16);
    s_ += __shfl_xor(s_,32); q_ += __shfl_xor(q_,32);
    if(lane < 16 && (lane&3)==0){
      int oc = (bn0 + wn*64 + b*16 + l15)>>2;
      atomicAdd(&ssum[oc], s_); atomicAdd(&ssq[oc], q_);
    }
  }
}

// ---------------------------------------------------------------------------
// fp32 row-sliced deconv (R3-proven) for L2.
template<int IC, int OC, int IH, int RB, int Lg, int Ko>
__global__ __launch_bounds__(256) void k_deconv3(const float* __restrict__ in,
    const float* __restrict__ w, float* __restrict__ out,
    float* __restrict__ ssum, float* __restrict__ ssq){
  constexpr int IW = IH, OW = 2*IH;
  constexpr int S = IH*IW;
  constexpr int Tt = RB*IW;
  static_assert(Tt*Lg == 256, "block mismatch");
  constexpr int SR = RB+2;
  constexpr int OCG = OC/(Lg*Ko);
  constexpr int IW4 = IW/4;
  __shared__ float lin[IC*SR*IW];

  int bx = blockIdx.x;
  int os = bx % OCG, rg = bx / OCG;
  int n = blockIdx.y;
  int tid = threadIdx.x;

  {
    const float4* src = (const float4*)in;
    float4* dst = (float4*)lin;
    constexpr int NV4 = IC*SR*IW4;
    static_assert(NV4 % 256 == 0, "stage divisibility");
    #pragma unroll
    for(int i=0;i<NV4/256;i++){
      int idx = tid + i*256;
      int ic = idx/(SR*IW4); int rem = idx - ic*(SR*IW4);
      int j = rem/IW4; int c4 = rem - j*IW4;
      int gr = RB*rg - 1 + j;
      gr = gr < 0 ? 0 : (gr > IH-1 ? IH-1 : gr);
      dst[idx] = src[((size_t)(n*IC+ic)*IH + gr)*IW4 + c4];
    }
  }
  __syncthreads();

  int lg = tid / Tt, t = tid % Tt;
  int tl = t / IW, tx = t % IW;
  int ty = RB*rg + tl;
  int oc0 = os*(Lg*Ko) + lg*Ko;

  int offs[3][3]; float msk[3][3];
  #pragma unroll
  for(int dy=0;dy<3;dy++){
    int iy = ty-1+dy; bool vy = (iy>=0)&&(iy<IH);
    #pragma unroll
    for(int dx=0;dx<3;dx++){
      int ix = tx-1+dx; bool vx = (ix>=0)&&(ix<IW);
      int lcol = ix < 0 ? 0 : (ix > IW-1 ? IW-1 : ix);
      offs[dy][dx] = (tl+dy)*IW + lcol;
      msk[dy][dx]  = (vy&&vx) ? 1.f : 0.f;
    }
  }

  float acc[Ko][2][2];
  #pragma unroll
  for(int ko=0;ko<Ko;ko++)
    #pragma unroll
    for(int r=0;r<2;r++){ acc[ko][r][0]=0.f; acc[ko][r][1]=0.f; }

  #pragma unroll 2
  for(int ic=0; ic<IC; ic++){
    const float* p = lin + ic*(SR*IW);
    float v[3][3];
    #pragma unroll
    for(int dy=0;dy<3;dy++)
      #pragma unroll
      for(int dx=0;dx<3;dx++)
        v[dy][dx] = p[offs[dy][dx]] * msk[dy][dx];
    const float4* wr = (const float4*)(w + ((size_t)ic*OC + oc0)*16);
    #pragma unroll
    for(int ko=0;ko<Ko;ko++){
      float4 w0=wr[ko*4+0], w1=wr[ko*4+1], w2=wr[ko*4+2], w3=wr[ko*4+3];
      float wv[16] = {w0.x,w0.y,w0.z,w0.w, w1.x,w1.y,w1.z,w1.w,
                      w2.x,w2.y,w2.z,w2.w, w3.x,w3.y,w3.z,w3.w};
      #pragma unroll
      for(int r=0;r<2;r++)
        #pragma unroll
        for(int s2=0;s2<2;s2++)
          #pragma unroll
          for(int a=0;a<2;a++)
            #pragma unroll
            for(int b2=0;b2<2;b2++)
              acc[ko][r][s2] = fmaf(v[a+r][b2+s2], wv[(3-2*a-r)*4 + (3-2*b2-s2)], acc[ko][r][s2]);
    }
  }

  #pragma unroll
  for(int ko=0;ko<Ko;ko++){
    float s_=0.f, q_=0.f;
    float* ob = out + ((size_t)n*OC + oc0+ko)*4*S;
    #pragma unroll
    for(int r=0;r<2;r++)
      #pragma unroll
      for(int s2=0;s2<2;s2++){
        float vv = acc[ko][r][s2];
        ob[(2*ty+r)*OW + (2*tx+s2)] = vv;
        s_ += vv; q_ = fmaf(vv,vv,q_);
      }
    #pragma unroll
    for(int m=1;m<64;m<<=1){ s_ += __shfl_xor(s_,m,64); q_ += __shfl_xor(q_,m,64); }
    if((t & 63)==0){ atomicAdd(&ssum[oc0+ko], s_); atomicAdd(&ssq[oc0+ko], q_); }
  }
}

// in-place BN(training stats) + leaky (R3-proven). x layout (N, OC, SP)
template<int OC, int SP>
__global__ void k_bn(float* __restrict__ x, const float* __restrict__ ssum,
                     const float* __restrict__ ssq, const float* __restrict__ g,
                     const float* __restrict__ be, int n4){
  int i = blockIdx.x*256 + threadIdx.x;
  if(i >= n4) return;
  int c = ((i*4)/SP) % OC;
  const float inv_cnt = 1.f/(640.f*SP);
  float m = ssum[c]*inv_cnt;
  float var = ssq[c]*inv_cnt - m*m;
  float sc = g[c]*rsqrtf(var + 1e-5f);
  float sh = be[c] - m*sc;
  float4 xv = ((float4*)x)[i];
  xv.x = lrelu(fmaf(xv.x, sc, sh));
  xv.y = lrelu(fmaf(xv.y, sc, sh));
  xv.z = lrelu(fmaf(xv.z, sc, sh));
  xv.w = lrelu(fmaf(xv.w, sc, sh));
  ((float4*)x)[i] = xv;
}

// ---------------------------------------------------------------------------
// final ConvTranspose (32->1) + sigmoid (R3-proven; reads post-BN conv2).
__global__ __launch_bounds__(256,3) void k_final(const float* __restrict__ in,
    const float* __restrict__ w, float* __restrict__ dout, const float* __restrict__ fb){
  constexpr int IC = 32, IH = 32, IW = 32, OW = 64, RB = 8, SR = RB+2;
  __shared__ float lin[IC*SR*IW];
  __shared__ __align__(16) float lw[IC*16];

  int rg = blockIdx.x;
  int n = blockIdx.y;
  int tid = threadIdx.x;

  {
    const float4* src = (const float4*)in;
    float4* dst = (float4*)lin;
    constexpr int NV4 = IC*SR*IW/4;
    #pragma unroll
    for(int i=0;i<NV4/256;i++){
      int idx = tid + i*256;
      int ic = idx/(SR*8); int rem = idx - ic*(SR*8);
      int j = rem/8; int c4 = rem - j*8;
      int gr = RB*rg - 1 + j;
      gr = gr < 0 ? 0 : (gr > IH-1 ? IH-1 : gr);
      dst[idx] = src[((size_t)(n*IC+ic)*IH + gr)*8 + c4];
    }
    if(tid < 128) ((float4*)lw)[tid] = ((const float4*)w)[tid];
  }
  float fbv = fb[0];
  __syncthreads();

  int tl = tid / IW, tx = tid % IW;
  int ty = RB*rg + tl;

  int offs[3][3]; float msk[3][3];
  #pragma unroll
  for(int dy=0;dy<3;dy++){
    int iy = ty-1+dy; bool vy = (iy>=0)&&(iy<IH);
    #pragma unroll
    for(int dx=0;dx<3;dx++){
      int ix = tx-1+dx; bool vx = (ix>=0)&&(ix<IW);
      int lcol = ix < 0 ? 0 : (ix > IW-1 ? IW-1 : ix);
      offs[dy][dx] = (tl+dy)*IW + lcol;
      msk[dy][dx]  = (vy&&vx) ? 1.f : 0.f;
    }
  }

  float acc[2][2] = {{0.f,0.f},{0.f,0.f}};
  #pragma unroll 4
  for(int ic=0; ic<IC; ic++){
    const float* p = lin + ic*(SR*IW);
    float v[3][3];
    #pragma unroll
    for(int dy=0;dy<3;dy++)
      #pragma unroll
      for(int dx=0;dx<3;dx++)
        v[dy][dx] = p[offs[dy][dx]] * msk[dy][dx];
    const float4* wr = (const float4*)(lw + ic*16);
    float4 w0=wr[0], w1=wr[1], w2=wr[2], w3=wr[3];
    float wv[16] = {w0.x,w0.y,w0.z,w0.w, w1.x,w1.y,w1.z,w1.w,
                    w2.x,w2.y,w2.z,w2.w, w3.x,w3.y,w3.z,w3.w};
    #pragma unroll
    for(int r=0;r<2;r++)
      #pragma unroll
      for(int s2=0;s2<2;s2++)
        #pragma unroll
        for(int a=0;a<2;a++)
          #pragma unroll
          for(int b2=0;b2<2;b2++)
            acc[r][s2] = fmaf(v[a+r][b2+s2], wv[(3-2*a-r)*4 + (3-2*b2-s2)], acc[r][s2]);
  }

  float* ob = dout + (size_t)n*OW*OW;
  #pragma unroll
  for(int r=0;r<2;r++)
    #pragma unroll
    for(int s2=0;s2<2;s2++){
      float vv = acc[r][s2] + fbv;
      ob[(2*ty+r)*OW + (2*tx+s2)] = 1.f/(1.f+__expf(-vv));
    }
}

extern "C" void kernel_launch(void* const* d_in, const int* in_sizes, int n_in,
                              void* d_out, int out_size, void* d_ws, size_t ws_size,
                              hipStream_t stream){
  const float* z       = (const float*)d_in[0];
  const float* fhw     = (const float*)d_in[1];
  const float* fhb     = (const float*)d_in[2];
  const float* fcw     = (const float*)d_in[3];
  const float* fcb     = (const float*)d_in[4];
  const float* wih     = (const float*)d_in[5];
  const float* bih     = (const float*)d_in[6];
  const float* whh     = (const float*)d_in[7];
  const float* bhh     = (const float*)d_in[8];
  const float* init_inp= (const float*)d_in[9];
  const float* fow     = (const float*)d_in[10];
  const float* fob     = (const float*)d_in[11];
  const float* cfw     = (const float*)d_in[12];
  const float* cfb     = (const float*)d_in[13];
  const float* dw0     = (const float*)d_in[14];
  const float* g0      = (const float*)d_in[15];
  const float* be0     = (const float*)d_in[16];
  const float* dw1     = (const float*)d_in[17];
  const float* g1      = (const float*)d_in[18];
  const float* be1     = (const float*)d_in[19];
  const float* dw2     = (const float*)d_in[20];
  const float* g2      = (const float*)d_in[21];
  const float* be2     = (const float*)d_in[22];
  const float* fw      = (const float*)d_in[23];
  const float* fb      = (const float*)d_in[24];

  float* ws    = (float*)d_ws;
  float* conv2 = ws;                 // 640*32*1024 = 20971520 floats
  float* conv1 = ws + 20971520;      // 640*64*256  = 10485760
  float* conv0 = ws + 31457280;      // 640*128*64  =  5242880
  float* fc1   = ws + 36700160;      // 640*4096    =  2621440
  float* feats = ws + 39321600;      // 640*512     =   327680
  float* outs  = ws + 39649280;      // 20*32*256   =   163840
  float* Wc    = ws + 39813120;      // 1024*256    =   262144
  float* bias0 = ws + 40075264;      // 1024
  float* bias1 = ws + 40076288;      // 1024
  float* h0    = ws + 40077312;      // 8192
  float* cbuf  = ws + 40085504;      // 8192
  float* stats = ws + 40093696;      // 448
  float* sum0 = stats,     *sq0 = stats+128;
  float* sum1 = stats+256, *sq1 = stats+320;
  float* sum2 = stats+384, *sq2 = stats+416;

  // transformed weights live in conv2 region (dead until L2 writes conv2)
  unsigned short* Wz0 = (unsigned short*)conv2;                 // 512*2304 f16
  unsigned short* Wz1 = (unsigned short*)(conv2 + 600000);      // 256*1152 f16

  hipLaunchKernelGGL(k_wc,    dim3(256), dim3(256), 0, stream, wih, whh, Wc);
  hipLaunchKernelGGL(k_bias,  dim3(4),   dim3(256), 0, stream, wih, bih, bhh, init_inp, bias0, bias1);
  hipLaunchKernelGGL(k_rowfc, dim3(32),  dim3(256), 0, stream, z, fhw, fhb, h0);
  hipLaunchKernelGGL(k_rowfc, dim3(32),  dim3(256), 0, stream, z, fcw, fcb, cbuf);
  hipLaunchKernelGGL(k_zero,  dim3(2),   dim3(256), 0, stream, stats, 448);

  for(int t=0;t<T_;t++){
    const float* W  = (t==0) ? whh   : Wc;
    const float* bs = (t==0) ? bias0 : bias1;
    const float* hp = (t==0) ? h0    : outs + (t-1)*B_*H_;
    hipLaunchKernelGGL(k_lstm, dim3(4,32), dim3(256), 0, stream, hp, cbuf, W, bs, outs + t*B_*H_);
  }

  hipLaunchKernelGGL(k_fcout, dim3(2,NT_), dim3(256), 0, stream, outs, fow, fob, feats);
  hipLaunchKernelGGL(k_cnnfc, dim3(4,80),  dim3(256), 0, stream, feats, cfw, cfb, fc1);

  hipLaunchKernelGGL((k_wz<256,128>), dim3(4608), dim3(256), 0, stream, dw0, Wz0);
  hipLaunchKernelGGL((k_wz<128,64>),  dim3(1152), dim3(256), 0, stream, dw1, Wz1);

  // L0 (MFMA): IC=256 OC=128 IH=4, NL=4 RB=4 SR=4 BM=64, grid(160,4)
  hipLaunchKernelGGL((k_gemmdc<256,128,4,4,4,4,64,false>), dim3(160,4), dim3(256), 0, stream,
                     fc1, Wz0, conv0, (const float*)nullptr, (const float*)nullptr, sum0, sq0);
  hipLaunchKernelGGL((k_bn<128,64>),   dim3(5120),  dim3(256), 0, stream, conv0, sum0, sq0, g0, be0, 1310720);

  // L1 (MFMA): IC=128 OC=64 IH=8, NL=2 RB=8 SR=8 BM=128, grid(320,2) — plain staging
  hipLaunchKernelGGL((k_gemmdc<128,64,8,2,8,8,128,false>), dim3(320,2), dim3(256), 0, stream,
                     conv0, Wz1, conv1, (const float*)nullptr, (const float*)nullptr, sum1, sq1);
  hipLaunchKernelGGL((k_bn<64,256>),   dim3(10240), dim3(256), 0, stream, conv1, sum1, sq1, g1, be1, 2621440);

  // L2 (fp32, R3-proven): IC=64 OC=32 IH=16 | RB=4 Lg=4 Ko=8 -> grid(4,640)
  hipLaunchKernelGGL((k_deconv3<64,32,16,4,4,8>), dim3(4,640), dim3(256), 0, stream,
                     conv1, dw2, conv2, sum2, sq2);
  hipLaunchKernelGGL((k_bn<32,1024>),  dim3(20480), dim3(256), 0, stream, conv2, sum2, sq2, g2, be2, 5242880);

  // final (R3-proven)
  hipLaunchKernelGGL(k_final, dim3(4,640), dim3(256), 0, stream, conv2, fw, (float*)d_out, fb);
}

// Round 8
// 1064.502 us; speedup vs baseline: 2.7761x; 1.8685x over previous
//
#include <hip/hip_runtime.h>
#include <math.h>

#define B_ 32
#define T_ 20
#define H_ 256
#define F_ 512
#define NT_ 640

typedef __attribute__((ext_vector_type(8))) _Float16 half8v;
typedef __attribute__((ext_vector_type(4))) float f32x4;

__device__ __forceinline__ float sigf(float x){ return 1.f/(1.f+__expf(-x)); }
__device__ __forceinline__ float lrelu(float x){ return x>0.f ? x : 0.2f*x; }
__device__ __forceinline__ float dot4(float4 a, float4 b){
  return fmaf(a.x,b.x, fmaf(a.y,b.y, fmaf(a.z,b.z, a.w*b.w)));
}
__device__ __forceinline__ unsigned short f16bits(float x){
  _Float16 h = (_Float16)x;                 // RNE
  union { _Float16 h; unsigned short u; } cv; cv.h = h; return cv.u;
}

// Wc = w_ih + w_hh
__global__ void k_wc(const float* __restrict__ wih, const float* __restrict__ whh,
                     float* __restrict__ Wc){
  int i = blockIdx.x*256 + threadIdx.x;
  float4 a = ((const float4*)wih)[i];
  float4 b = ((const float4*)whh)[i];
  ((float4*)Wc)[i] = make_float4(a.x+b.x, a.y+b.y, a.z+b.z, a.w+b.w);
}

// bias1 = b_ih + b_hh ; bias0 = init_inp @ w_ih.T + bias1
__global__ void k_bias(const float* __restrict__ wih, const float* __restrict__ bih,
                       const float* __restrict__ bhh, const float* __restrict__ init_inp,
                       float* __restrict__ bias0, float* __restrict__ bias1){
  __shared__ __align__(16) float xs[H_];
  int tid = threadIdx.x;
  xs[tid] = init_inp[tid];
  __syncthreads();
  int j = blockIdx.x*256 + tid;
  const float4* wr = (const float4*)(wih + (size_t)j*H_);
  const float4* xx = (const float4*)xs;
  float acc = 0.f;
  #pragma unroll 8
  for(int k=0;k<H_/4;k++) acc += dot4(wr[k], xx[k]);
  float b1 = bih[j] + bhh[j];
  bias1[j] = b1;
  bias0[j] = acc + b1;
}

// out[b][j] = z[b] . W[j] + bias[j]
__global__ void k_rowfc(const float* __restrict__ z, const float* __restrict__ W,
                        const float* __restrict__ bias, float* __restrict__ out){
  __shared__ __align__(16) float zs[H_];
  int b = blockIdx.x, j = threadIdx.x;
  zs[j] = z[b*H_ + j];
  __syncthreads();
  const float4* wr = (const float4*)(W + (size_t)j*H_);
  const float4* zz = (const float4*)zs;
  float acc = bias[j];
  #pragma unroll 8
  for(int k=0;k<H_/4;k++) acc += dot4(wr[k], zz[k]);
  out[b*H_+j] = acc;
}

__global__ void k_zero(float* p, int n){
  int i = blockIdx.x*256 + threadIdx.x;
  if(i<n) p[i]=0.f;
}

// one LSTM step
__global__ void k_lstm(const float* __restrict__ hprev, float* __restrict__ c,
                       const float* __restrict__ W, const float* __restrict__ bias,
                       float* __restrict__ hout){
  __shared__ __align__(16) float hs[H_];
  __shared__ float gs[4][64];
  int b = blockIdx.y, jg = blockIdx.x, tid = threadIdx.x;
  hs[tid] = hprev[b*H_ + tid];
  __syncthreads();
  int g = tid>>6, jj = tid&63;
  int row = g*H_ + jg*64 + jj;
  const float4* wr = (const float4*)(W + (size_t)row*H_);
  const float4* hh = (const float4*)hs;
  float acc = bias[row];
  #pragma unroll 8
  for(int k=0;k<H_/4;k++) acc += dot4(wr[k], hh[k]);
  gs[g][jj] = acc;
  __syncthreads();
  if(tid < 64){
    int j = jg*64 + tid;
    float iv = gs[0][tid], fv = gs[1][tid], gv = gs[2][tid], ov = gs[3][tid];
    int ci = b*H_ + j;
    float cn = sigf(fv)*c[ci] + sigf(iv)*tanhf(gv);
    c[ci] = cn;
    hout[b*H_ + j] = sigf(ov)*tanhf(cn);
  }
}

// feats[n][f] = leaky(outs[t][b] . w[f] + bias[f]),  n = b*T+t
__global__ void k_fcout(const float* __restrict__ outs, const float* __restrict__ w,
                        const float* __restrict__ bias, float* __restrict__ feats){
  __shared__ __align__(16) float hs[H_];
  int n = blockIdx.y; int b = n/T_, t = n - b*T_;
  int tid = threadIdx.x;
  hs[tid] = outs[(t*B_ + b)*H_ + tid];
  __syncthreads();
  int f = blockIdx.x*256 + tid;
  const float4* wr = (const float4*)(w + (size_t)f*H_);
  const float4* hh = (const float4*)hs;
  float acc = bias[f];
  #pragma unroll 8
  for(int k=0;k<H_/4;k++) acc += dot4(wr[k], hh[k]);
  feats[n*F_ + f] = lrelu(acc);
}

// fc1[n][oc] = leaky(feats[n] . w[oc] + b[oc])
__global__ __launch_bounds__(256) void k_cnnfc(const float* __restrict__ feats,
    const float* __restrict__ w, const float* __restrict__ bias, float* __restrict__ out){
  __shared__ __align__(16) float fe[8*F_];
  int ocg = blockIdx.x, ng = blockIdx.y, tid = threadIdx.x;
  const float4* src = (const float4*)(feats + (size_t)ng*8*F_);
  float4* dst = (float4*)fe;
  for(int i=tid;i<8*F_/4;i+=256) dst[i] = src[i];
  __syncthreads();
  int oc0 = ocg*1024 + tid;
  const float4* w0 = (const float4*)(w + (size_t)(oc0      )*F_);
  const float4* w1 = (const float4*)(w + (size_t)(oc0+256 )*F_);
  const float4* w2 = (const float4*)(w + (size_t)(oc0+512 )*F_);
  const float4* w3 = (const float4*)(w + (size_t)(oc0+768 )*F_);
  float acc[4][8];
  #pragma unroll
  for(int i=0;i<4;i++){
    float bv = bias[oc0 + i*256];
    #pragma unroll
    for(int nn=0;nn<8;nn++) acc[i][nn]=bv;
  }
  for(int k=0;k<F_/4;k++){
    float4 wv0=w0[k], wv1=w1[k], wv2=w2[k], wv3=w3[k];
    #pragma unroll
    for(int nn=0;nn<8;nn++){
      float4 f = ((const float4*)(fe + nn*F_))[k];
      acc[0][nn] += dot4(wv0,f);
      acc[1][nn] += dot4(wv1,f);
      acc[2][nn] += dot4(wv2,f);
      acc[3][nn] += dot4(wv3,f);
    }
  }
  #pragma unroll
  for(int i=0;i<4;i++)
    #pragma unroll
    for(int nn=0;nn<8;nn++)
      out[(size_t)(ng*8+nn)*4096 + ocg*1024 + i*256 + tid] = lrelu(acc[i][nn]);
}

// ---------------------------------------------------------------------------
// weight transform: Wz[n=(oc*4+py*2+px)][k=(dy3*3+dx3)*IC+ic] (fp16, k-fastest)
template<int IC, int OC>
__global__ void k_wz(const float* __restrict__ w, unsigned short* __restrict__ Wz){
  constexpr int K9 = 9*IC, N4 = 4*OC;
  int i = blockIdx.x*256 + threadIdx.x;
  if(i >= N4*K9) return;
  int n = i / K9; int k = i - n*K9;
  int oc = n>>2, py = (n>>1)&1, px = n&1;
  int dd = k / IC; int ic = k - dd*IC;
  int dy3 = dd/3, dx3 = dd - 3*dy3;
  int ky = py + 3 - 2*dy3, kx = px + 3 - 2*dx3;
  float v = 0.f;
  if(ky>=0 && ky<4 && kx>=0 && kx<4)
    v = w[(((size_t)ic*OC + oc)*4 + ky)*4 + kx];
  Wz[i] = f16bits(v);
}

// ---------------------------------------------------------------------------
// MFMA implicit-GEMM deconv, SPLIT-fp16 activations (A = hi + lo, fp32-exact).
template<int IC, int OC, int IH, int NL, int RB, int SR, int BM, bool BNIN>
__global__ __launch_bounds__(256) void k_gemmdc(
    const float* __restrict__ in, const unsigned short* __restrict__ Wz,
    float* __restrict__ out, const float* __restrict__ sc, const float* __restrict__ sh,
    float* __restrict__ ssum, float* __restrict__ ssq)
{
  constexpr int IW = IH, OW = 2*IH;
  constexpr int S  = IH*IW, S4 = 4*S;
  constexpr int K9 = 9*IC;
  constexpr int ICp = IC + 8;
  constexpr int TS = IH/RB;
  constexpr int P  = NL*SR*IW;
  constexpr int NK = K9/32;
  constexpr int BN = 128;
  constexpr int AM = BM/32;
  static_assert(NL*RB*IW == BM, "BM mismatch");

  __shared__ unsigned short linH[P*ICp];
  __shared__ unsigned short linL[P*ICp];
  __shared__ unsigned short bt[BN*32];

  const int tid = threadIdx.x;
  const int bm = blockIdx.x, bn0 = blockIdx.y*BN;
  const int nimg0 = (bm/TS)*NL;
  const int rg = bm % TS;
  const int W0 = (SR==IH) ? 0 : (rg*RB - 1);

  {
    constexpr int NIT = P*(IC/8)/256;
    #pragma unroll
    for(int it=0; it<NIT; ++it){
      int i = tid + it*256;
      int p = i % P; int icb = (i/P)*8;
      int x = p % IW; int t1 = p/IW; int j = t1 % SR; int nl = t1/SR;
      int gr = W0 + j;
      bool ok = (gr>=0) && (gr<IH);
      const float* src = in + ((size_t)(nimg0+nl)*IC + icb)*S + gr*IW + x;
      unsigned short hh[8], ll[8];
      #pragma unroll
      for(int e=0;e<8;e++){
        float v = ok ? src[(size_t)e*S] : 0.f;
        if(BNIN) v = lrelu(fmaf(v, sc[icb+e], sh[icb+e]));
        _Float16 hi = (_Float16)v;
        float lo = v - (float)hi;
        union { _Float16 h; unsigned short u; } c1, c2;
        c1.h = hi; c2.h = (_Float16)lo;
        hh[e] = c1.u; ll[e] = c2.u;
      }
      *(uint4*)&linH[p*ICp + icb] = *(uint4*)hh;
      *(uint4*)&linL[p*ICp + icb] = *(uint4*)ll;
    }
  }

  const int lane = tid & 63, wvi = tid>>6;
  const int wm = wvi>>1, wn = wvi&1;
  const int l15 = lane & 15, lh = lane>>4;

  int mxA[AM], mylA[AM], nlA[AM];
  #pragma unroll
  for(int a=0;a<AM;a++){
    int r = wm*(BM/2) + a*16 + l15;
    mxA[a] = r % IW; int t = r/IW; mylA[a] = t % RB; nlA[a] = t/RB;
  }

  f32x4 acc[AM][4] = {};

  for(int ks=0; ks<NK; ++ks){
    __syncthreads();
    #pragma unroll
    for(int q=0;q<2;q++){
      int idx = tid + q*256;
      int n = idx>>2, h = idx&3;
      const uint4* s4p = (const uint4*)(Wz + (size_t)(bn0+n)*K9 + ks*32 + h*8);
      *(uint4*)&bt[n*32 + h*8] = *s4p;
    }
    __syncthreads();

    int k0 = ks*32;
    int dd = k0 / IC; int icb = k0 - dd*IC;
    int dy3 = dd/3, dx3 = dd - 3*dy3;

    half8v AfH[AM], AfL[AM], Bf[4];
    #pragma unroll
    for(int a=0;a<AM;a++){
      int gx = mxA[a] - 1 + dx3;
      bool vx = (gx>=0) && (gx<IW);
      int gxc = gx<0 ? 0 : (gx>IW-1 ? IW-1 : gx);
      int jyc; bool vy;
      if(SR==IH){
        int jy = mylA[a] - 1 + dy3;
        vy = (jy>=0) && (jy<IH);
        jyc = jy<0 ? 0 : (jy>SR-1 ? SR-1 : jy);
      } else {
        jyc = mylA[a] + dy3; vy = true;   // halo rows staged (zero-filled OOB)
      }
      int p = (nlA[a]*SR + jyc)*IW + gxc;
      half8v fH = *(const half8v*)&linH[p*ICp + icb + lh*8];
      half8v fL = *(const half8v*)&linL[p*ICp + icb + lh*8];
      if(!(vx&&vy)){
        #pragma unroll
        for(int e=0;e<8;e++){ fH[e] = (_Float16)0.f; fL[e] = (_Float16)0.f; }
      }
      AfH[a] = fH; AfL[a] = fL;
    }
    #pragma unroll
    for(int b=0;b<4;b++)
      Bf[b] = *(const half8v*)&bt[(wn*64 + b*16 + l15)*32 + lh*8];

    #pragma unroll
    for(int a=0;a<AM;a++)
      #pragma unroll
      for(int b=0;b<4;b++){
        acc[a][b] = __builtin_amdgcn_mfma_f32_16x16x32_f16(AfH[a], Bf[b], acc[a][b], 0, 0, 0);
        acc[a][b] = __builtin_amdgcn_mfma_f32_16x16x32_f16(AfL[a], Bf[b], acc[a][b], 0, 0, 0);
      }
  }

  float sb[4] = {0,0,0,0}, qb[4] = {0,0,0,0};
  #pragma unroll
  for(int b=0;b<4;b++){
    int nidx = bn0 + wn*64 + b*16 + l15;
    int oc = nidx>>2, py = (nidx>>1)&1, px = nidx&1;
    #pragma unroll
    for(int a=0;a<AM;a++){
      f32x4 c = acc[a][b];
      #pragma unroll
      for(int r=0;r<4;r++){
        int rr = wm*(BM/2) + a*16 + lh*4 + r;
        int mx = rr % IW; int t = rr/IW; int myl = t % RB; int nl = t/RB;
        int myg = (SR==IH) ? myl : (rg*RB + myl);
        float v = c[r];
        out[((size_t)(nimg0+nl)*OC + oc)*S4 + (size_t)(2*myg+py)*OW + (2*mx+px)] = v;
        sb[b] += v; qb[b] = fmaf(v,v,qb[b]);
      }
    }
  }
  #pragma unroll
  for(int b=0;b<4;b++){
    float s_ = sb[b], q_ = qb[b];
    s_ += __shfl_xor(s_,1);  q_ += __shfl_xor(q_,1);
    s_ += __shfl_xor(s_,2);  q_ += __shfl_xor(q_,2);
    s_ += __shfl_xor(s_,16); q_ += __shfl_xor(q_,16);
    s_ += __shfl_xor(s_,32); q_ += __shfl_xor(q_,32);
    if(lane < 16 && (lane&3)==0){
      int oc = (bn0 + wn*64 + b*16 + l15)>>2;
      atomicAdd(&ssum[oc], s_); atomicAdd(&ssq[oc], q_);
    }
  }
}

// in-place BN(training stats) + leaky (R3-proven). x layout (N, OC, SP)
template<int OC, int SP>
__global__ void k_bn(float* __restrict__ x, const float* __restrict__ ssum,
                     const float* __restrict__ ssq, const float* __restrict__ g,
                     const float* __restrict__ be, int n4){
  int i = blockIdx.x*256 + threadIdx.x;
  if(i >= n4) return;
  int c = ((i*4)/SP) % OC;
  const float inv_cnt = 1.f/(640.f*SP);
  float m = ssum[c]*inv_cnt;
  float var = ssq[c]*inv_cnt - m*m;
  float sc = g[c]*rsqrtf(var + 1e-5f);
  float sh = be[c] - m*sc;
  float4 xv = ((float4*)x)[i];
  xv.x = lrelu(fmaf(xv.x, sc, sh));
  xv.y = lrelu(fmaf(xv.y, sc, sh));
  xv.z = lrelu(fmaf(xv.z, sc, sh));
  xv.w = lrelu(fmaf(xv.w, sc, sh));
  ((float4*)x)[i] = xv;
}

// ---------------------------------------------------------------------------
// final ConvTranspose (32->1) + sigmoid (R3-proven; reads post-BN conv2).
__global__ __launch_bounds__(256,3) void k_final(const float* __restrict__ in,
    const float* __restrict__ w, float* __restrict__ dout, const float* __restrict__ fb){
  constexpr int IC = 32, IH = 32, IW = 32, OW = 64, RB = 8, SR = RB+2;
  __shared__ float lin[IC*SR*IW];
  __shared__ __align__(16) float lw[IC*16];

  int rg = blockIdx.x;
  int n = blockIdx.y;
  int tid = threadIdx.x;

  {
    const float4* src = (const float4*)in;
    float4* dst = (float4*)lin;
    constexpr int NV4 = IC*SR*IW/4;
    #pragma unroll
    for(int i=0;i<NV4/256;i++){
      int idx = tid + i*256;
      int ic = idx/(SR*8); int rem = idx - ic*(SR*8);
      int j = rem/8; int c4 = rem - j*8;
      int gr = RB*rg - 1 + j;
      gr = gr < 0 ? 0 : (gr > IH-1 ? IH-1 : gr);
      dst[idx] = src[((size_t)(n*IC+ic)*IH + gr)*8 + c4];
    }
    if(tid < 128) ((float4*)lw)[tid] = ((const float4*)w)[tid];
  }
  float fbv = fb[0];
  __syncthreads();

  int tl = tid / IW, tx = tid % IW;
  int ty = RB*rg + tl;

  int offs[3][3]; float msk[3][3];
  #pragma unroll
  for(int dy=0;dy<3;dy++){
    int iy = ty-1+dy; bool vy = (iy>=0)&&(iy<IH);
    #pragma unroll
    for(int dx=0;dx<3;dx++){
      int ix = tx-1+dx; bool vx = (ix>=0)&&(ix<IW);
      int lcol = ix < 0 ? 0 : (ix > IW-1 ? IW-1 : ix);
      offs[dy][dx] = (tl+dy)*IW + lcol;
      msk[dy][dx]  = (vy&&vx) ? 1.f : 0.f;
    }
  }

  float acc[2][2] = {{0.f,0.f},{0.f,0.f}};
  #pragma unroll 4
  for(int ic=0; ic<IC; ic++){
    const float* p = lin + ic*(SR*IW);
    float v[3][3];
    #pragma unroll
    for(int dy=0;dy<3;dy++)
      #pragma unroll
      for(int dx=0;dx<3;dx++)
        v[dy][dx] = p[offs[dy][dx]] * msk[dy][dx];
    const float4* wr = (const float4*)(lw + ic*16);
    float4 w0=wr[0], w1=wr[1], w2=wr[2], w3=wr[3];
    float wv[16] = {w0.x,w0.y,w0.z,w0.w, w1.x,w1.y,w1.z,w1.w,
                    w2.x,w2.y,w2.z,w2.w, w3.x,w3.y,w3.z,w3.w};
    #pragma unroll
    for(int r=0;r<2;r++)
      #pragma unroll
      for(int s2=0;s2<2;s2++)
        #pragma unroll
        for(int a=0;a<2;a++)
          #pragma unroll
          for(int b2=0;b2<2;b2++)
            acc[r][s2] = fmaf(v[a+r][b2+s2], wv[(3-2*a-r)*4 + (3-2*b2-s2)], acc[r][s2]);
  }

  float* ob = dout + (size_t)n*OW*OW;
  #pragma unroll
  for(int r=0;r<2;r++)
    #pragma unroll
    for(int s2=0;s2<2;s2++){
      float vv = acc[r][s2] + fbv;
      ob[(2*ty+r)*OW + (2*tx+s2)] = 1.f/(1.f+__expf(-vv));
    }
}

extern "C" void kernel_launch(void* const* d_in, const int* in_sizes, int n_in,
                              void* d_out, int out_size, void* d_ws, size_t ws_size,
                              hipStream_t stream){
  const float* z       = (const float*)d_in[0];
  const float* fhw     = (const float*)d_in[1];
  const float* fhb     = (const float*)d_in[2];
  const float* fcw     = (const float*)d_in[3];
  const float* fcb     = (const float*)d_in[4];
  const float* wih     = (const float*)d_in[5];
  const float* bih     = (const float*)d_in[6];
  const float* whh     = (const float*)d_in[7];
  const float* bhh     = (const float*)d_in[8];
  const float* init_inp= (const float*)d_in[9];
  const float* fow     = (const float*)d_in[10];
  const float* fob     = (const float*)d_in[11];
  const float* cfw     = (const float*)d_in[12];
  const float* cfb     = (const float*)d_in[13];
  const float* dw0     = (const float*)d_in[14];
  const float* g0      = (const float*)d_in[15];
  const float* be0     = (const float*)d_in[16];
  const float* dw1     = (const float*)d_in[17];
  const float* g1      = (const float*)d_in[18];
  const float* be1     = (const float*)d_in[19];
  const float* dw2     = (const float*)d_in[20];
  const float* g2      = (const float*)d_in[21];
  const float* be2     = (const float*)d_in[22];
  const float* fw      = (const float*)d_in[23];
  const float* fb      = (const float*)d_in[24];

  float* ws    = (float*)d_ws;
  float* conv2 = ws;                 // 640*32*1024 = 20971520 floats
  float* conv1 = ws + 20971520;      // 640*64*256  = 10485760
  float* conv0 = ws + 31457280;      // 640*128*64  =  5242880
  float* fc1   = ws + 36700160;      // 640*4096    =  2621440
  float* feats = ws + 39321600;      // 640*512     =   327680
  float* outs  = ws + 39649280;      // 20*32*256   =   163840
  float* Wc    = ws + 39813120;      // 1024*256    =   262144
  float* bias0 = ws + 40075264;      // 1024
  float* bias1 = ws + 40076288;      // 1024
  float* h0    = ws + 40077312;      // 8192
  float* cbuf  = ws + 40085504;      // 8192
  float* stats = ws + 40093696;      // 448
  float* sum0 = stats,     *sq0 = stats+128;
  float* sum1 = stats+256, *sq1 = stats+320;
  float* sum2 = stats+384, *sq2 = stats+416;

  // transformed weights live in regions dead at their use time:
  //  Wz0/Wz1 in conv2 (dead before L2 writes conv2); Wz2 in feats (dead after k_cnnfc)
  unsigned short* Wz0 = (unsigned short*)conv2;                 // 512*2304 f16
  unsigned short* Wz1 = (unsigned short*)(conv2 + 600000);      // 256*1152 f16
  unsigned short* Wz2 = (unsigned short*)feats;                 // 128*576 f16

  hipLaunchKernelGGL(k_wc,    dim3(256), dim3(256), 0, stream, wih, whh, Wc);
  hipLaunchKernelGGL(k_bias,  dim3(4),   dim3(256), 0, stream, wih, bih, bhh, init_inp, bias0, bias1);
  hipLaunchKernelGGL(k_rowfc, dim3(32),  dim3(256), 0, stream, z, fhw, fhb, h0);
  hipLaunchKernelGGL(k_rowfc, dim3(32),  dim3(256), 0, stream, z, fcw, fcb, cbuf);
  hipLaunchKernelGGL(k_zero,  dim3(2),   dim3(256), 0, stream, stats, 448);

  for(int t=0;t<T_;t++){
    const float* W  = (t==0) ? whh   : Wc;
    const float* bs = (t==0) ? bias0 : bias1;
    const float* hp = (t==0) ? h0    : outs + (t-1)*B_*H_;
    hipLaunchKernelGGL(k_lstm, dim3(4,32), dim3(256), 0, stream, hp, cbuf, W, bs, outs + t*B_*H_);
  }

  hipLaunchKernelGGL(k_fcout, dim3(2,NT_), dim3(256), 0, stream, outs, fow, fob, feats);
  hipLaunchKernelGGL(k_cnnfc, dim3(4,80),  dim3(256), 0, stream, feats, cfw, cfb, fc1);

  hipLaunchKernelGGL((k_wz<256,128>), dim3(4608), dim3(256), 0, stream, dw0, Wz0);
  hipLaunchKernelGGL((k_wz<128,64>),  dim3(1152), dim3(256), 0, stream, dw1, Wz1);
  hipLaunchKernelGGL((k_wz<64,32>),   dim3(288),  dim3(256), 0, stream, dw2, Wz2);

  // L0 (MFMA): IC=256 OC=128 IH=4, NL=4 RB=4 SR=4 BM=64, grid(160,4)
  hipLaunchKernelGGL((k_gemmdc<256,128,4,4,4,4,64,false>), dim3(160,4), dim3(256), 0, stream,
                     fc1, Wz0, conv0, (const float*)nullptr, (const float*)nullptr, sum0, sq0);
  hipLaunchKernelGGL((k_bn<128,64>),   dim3(5120),  dim3(256), 0, stream, conv0, sum0, sq0, g0, be0, 1310720);

  // L1 (MFMA): IC=128 OC=64 IH=8, NL=2 RB=8 SR=8 BM=128, grid(320,2)
  hipLaunchKernelGGL((k_gemmdc<128,64,8,2,8,8,128,false>), dim3(320,2), dim3(256), 0, stream,
                     conv0, Wz1, conv1, (const float*)nullptr, (const float*)nullptr, sum1, sq1);
  hipLaunchKernelGGL((k_bn<64,256>),   dim3(10240), dim3(256), 0, stream, conv1, sum1, sq1, g1, be1, 2621440);

  // L2 (MFMA, halo path under test): IC=64 OC=32 IH=16, NL=1 RB=8 SR=10 BM=128, grid(1280,1)
  hipLaunchKernelGGL((k_gemmdc<64,32,16,1,8,10,128,false>), dim3(1280,1), dim3(256), 0, stream,
                     conv1, Wz2, conv2, (const float*)nullptr, (const float*)nullptr, sum2, sq2);
  hipLaunchKernelGGL((k_bn<32,1024>),  dim3(20480), dim3(256), 0, stream, conv2, sum2, sq2, g2, be2, 5242880);

  // final (R3-proven)
  hipLaunchKernelGGL(k_final, dim3(4,640), dim3(256), 0, stream, conv2, fw, (float*)d_out, fb);
}

// Round 9
// 1014.540 us; speedup vs baseline: 2.9129x; 1.0492x over previous
//
#include <hip/hip_runtime.h>
#include <math.h>

#define B_ 32
#define T_ 20
#define H_ 256
#define F_ 512
#define NT_ 640

typedef __attribute__((ext_vector_type(8))) _Float16 half8v;
typedef __attribute__((ext_vector_type(4))) float f32x4;

__device__ __forceinline__ float sigf(float x){ return 1.f/(1.f+__expf(-x)); }
__device__ __forceinline__ float lrelu(float x){ return x>0.f ? x : 0.2f*x; }
__device__ __forceinline__ float dot4(float4 a, float4 b){
  return fmaf(a.x,b.x, fmaf(a.y,b.y, fmaf(a.z,b.z, a.w*b.w)));
}
__device__ __forceinline__ unsigned short f16bits(float x){
  _Float16 h = (_Float16)x;                 // RNE
  union { _Float16 h; unsigned short u; } cv; cv.h = h; return cv.u;
}

// Wc = w_ih + w_hh
__global__ void k_wc(const float* __restrict__ wih, const float* __restrict__ whh,
                     float* __restrict__ Wc){
  int i = blockIdx.x*256 + threadIdx.x;
  float4 a = ((const float4*)wih)[i];
  float4 b = ((const float4*)whh)[i];
  ((float4*)Wc)[i] = make_float4(a.x+b.x, a.y+b.y, a.z+b.z, a.w+b.w);
}

// bias1 = b_ih + b_hh ; bias0 = init_inp @ w_ih.T + bias1
__global__ void k_bias(const float* __restrict__ wih, const float* __restrict__ bih,
                       const float* __restrict__ bhh, const float* __restrict__ init_inp,
                       float* __restrict__ bias0, float* __restrict__ bias1){
  __shared__ __align__(16) float xs[H_];
  int tid = threadIdx.x;
  xs[tid] = init_inp[tid];
  __syncthreads();
  int j = blockIdx.x*256 + tid;
  const float4* wr = (const float4*)(wih + (size_t)j*H_);
  const float4* xx = (const float4*)xs;
  float acc = 0.f;
  #pragma unroll 8
  for(int k=0;k<H_/4;k++) acc += dot4(wr[k], xx[k]);
  float b1 = bih[j] + bhh[j];
  bias1[j] = b1;
  bias0[j] = acc + b1;
}

// out[b][j] = z[b] . W[j] + bias[j]
__global__ void k_rowfc(const float* __restrict__ z, const float* __restrict__ W,
                        const float* __restrict__ bias, float* __restrict__ out){
  __shared__ __align__(16) float zs[H_];
  int b = blockIdx.x, j = threadIdx.x;
  zs[j] = z[b*H_ + j];
  __syncthreads();
  const float4* wr = (const float4*)(W + (size_t)j*H_);
  const float4* zz = (const float4*)zs;
  float acc = bias[j];
  #pragma unroll 8
  for(int k=0;k<H_/4;k++) acc += dot4(wr[k], zz[k]);
  out[b*H_+j] = acc;
}

__global__ void k_zero(float* p, int n){
  int i = blockIdx.x*256 + threadIdx.x;
  if(i<n) p[i]=0.f;
}

// one LSTM step
__global__ void k_lstm(const float* __restrict__ hprev, float* __restrict__ c,
                       const float* __restrict__ W, const float* __restrict__ bias,
                       float* __restrict__ hout){
  __shared__ __align__(16) float hs[H_];
  __shared__ float gs[4][64];
  int b = blockIdx.y, jg = blockIdx.x, tid = threadIdx.x;
  hs[tid] = hprev[b*H_ + tid];
  __syncthreads();
  int g = tid>>6, jj = tid&63;
  int row = g*H_ + jg*64 + jj;
  const float4* wr = (const float4*)(W + (size_t)row*H_);
  const float4* hh = (const float4*)hs;
  float acc = bias[row];
  #pragma unroll 8
  for(int k=0;k<H_/4;k++) acc += dot4(wr[k], hh[k]);
  gs[g][jj] = acc;
  __syncthreads();
  if(tid < 64){
    int j = jg*64 + tid;
    float iv = gs[0][tid], fv = gs[1][tid], gv = gs[2][tid], ov = gs[3][tid];
    int ci = b*H_ + j;
    float cn = sigf(fv)*c[ci] + sigf(iv)*tanhf(gv);
    c[ci] = cn;
    hout[b*H_ + j] = sigf(ov)*tanhf(cn);
  }
}

// feats[n][f] = leaky(outs[t][b] . w[f] + bias[f]),  n = b*T+t
__global__ void k_fcout(const float* __restrict__ outs, const float* __restrict__ w,
                        const float* __restrict__ bias, float* __restrict__ feats){
  __shared__ __align__(16) float hs[H_];
  int n = blockIdx.y; int b = n/T_, t = n - b*T_;
  int tid = threadIdx.x;
  hs[tid] = outs[(t*B_ + b)*H_ + tid];
  __syncthreads();
  int f = blockIdx.x*256 + tid;
  const float4* wr = (const float4*)(w + (size_t)f*H_);
  const float4* hh = (const float4*)hs;
  float acc = bias[f];
  #pragma unroll 8
  for(int k=0;k<H_/4;k++) acc += dot4(wr[k], hh[k]);
  feats[n*F_ + f] = lrelu(acc);
}

// fc1[n][oc] = leaky(feats[n] . w[oc] + b[oc])
__global__ __launch_bounds__(256) void k_cnnfc(const float* __restrict__ feats,
    const float* __restrict__ w, const float* __restrict__ bias, float* __restrict__ out){
  __shared__ __align__(16) float fe[8*F_];
  int ocg = blockIdx.x, ng = blockIdx.y, tid = threadIdx.x;
  const float4* src = (const float4*)(feats + (size_t)ng*8*F_);
  float4* dst = (float4*)fe;
  for(int i=tid;i<8*F_/4;i+=256) dst[i] = src[i];
  __syncthreads();
  int oc0 = ocg*1024 + tid;
  const float4* w0 = (const float4*)(w + (size_t)(oc0      )*F_);
  const float4* w1 = (const float4*)(w + (size_t)(oc0+256 )*F_);
  const float4* w2 = (const float4*)(w + (size_t)(oc0+512 )*F_);
  const float4* w3 = (const float4*)(w + (size_t)(oc0+768 )*F_);
  float acc[4][8];
  #pragma unroll
  for(int i=0;i<4;i++){
    float bv = bias[oc0 + i*256];
    #pragma unroll
    for(int nn=0;nn<8;nn++) acc[i][nn]=bv;
  }
  for(int k=0;k<F_/4;k++){
    float4 wv0=w0[k], wv1=w1[k], wv2=w2[k], wv3=w3[k];
    #pragma unroll
    for(int nn=0;nn<8;nn++){
      float4 f = ((const float4*)(fe + nn*F_))[k];
      acc[0][nn] += dot4(wv0,f);
      acc[1][nn] += dot4(wv1,f);
      acc[2][nn] += dot4(wv2,f);
      acc[3][nn] += dot4(wv3,f);
    }
  }
  #pragma unroll
  for(int i=0;i<4;i++)
    #pragma unroll
    for(int nn=0;nn<8;nn++)
      out[(size_t)(ng*8+nn)*4096 + ocg*1024 + i*256 + tid] = lrelu(acc[i][nn]);
}

// ---------------------------------------------------------------------------
// weight transform: Wz[n=(oc*4+py*2+px)][k=(dy3*3+dx3)*IC+ic] (fp16, k-fastest)
template<int IC, int OC>
__global__ void k_wz(const float* __restrict__ w, unsigned short* __restrict__ Wz){
  constexpr int K9 = 9*IC, N4 = 4*OC;
  int i = blockIdx.x*256 + threadIdx.x;
  if(i >= N4*K9) return;
  int n = i / K9; int k = i - n*K9;
  int oc = n>>2, py = (n>>1)&1, px = n&1;
  int dd = k / IC; int ic = k - dd*IC;
  int dy3 = dd/3, dx3 = dd - 3*dy3;
  int ky = py + 3 - 2*dy3, kx = px + 3 - 2*dx3;
  float v = 0.f;
  if(ky>=0 && ky<4 && kx>=0 && kx<4)
    v = w[(((size_t)ic*OC + oc)*4 + ky)*4 + kx];
  Wz[i] = f16bits(v);
}

// ---------------------------------------------------------------------------
// MFMA implicit-GEMM deconv, fp16 operands (hi-only), fp32 accum.
// B-tile register-prefetched across K-steps to hide L2 latency.
template<int IC, int OC, int IH, int NL, int RB, int SR, int BM, bool BNIN>
__global__ __launch_bounds__(256) void k_gemmdc(
    const float* __restrict__ in, const unsigned short* __restrict__ Wz,
    float* __restrict__ out, const float* __restrict__ sc, const float* __restrict__ sh,
    float* __restrict__ ssum, float* __restrict__ ssq)
{
  constexpr int IW = IH, OW = 2*IH;
  constexpr int S  = IH*IW, S4 = 4*S;
  constexpr int K9 = 9*IC;
  constexpr int ICp = IC + 8;
  constexpr int TS = IH/RB;
  constexpr int P  = NL*SR*IW;
  constexpr int NK = K9/32;
  constexpr int BN = 128;
  constexpr int AM = BM/32;
  static_assert(NL*RB*IW == BM, "BM mismatch");

  __shared__ unsigned short linH[P*ICp];
  __shared__ unsigned short bt[BN*32];

  const int tid = threadIdx.x;
  const int bm = blockIdx.x, bn0 = blockIdx.y*BN;
  const int nimg0 = (bm/TS)*NL;
  const int rg = bm % TS;
  const int W0 = (SR==IH) ? 0 : (rg*RB - 1);

  // B prefetch addressing: thread covers (n = tid>>1, halves h2 = tid&1 -> 16 k)
  const int pf_n = tid>>1, pf_h = tid&1;
  const uint4* pf_base = (const uint4*)(Wz + (size_t)(bn0+pf_n)*K9 + pf_h*16);
  uint4 breg0, breg1;

  // ---- stage A slab (fp16 channel-last), fused BN+leaky if BNIN
  {
    constexpr int NIT = P*(IC/8)/256;
    #pragma unroll
    for(int it=0; it<NIT; ++it){
      int i = tid + it*256;
      int p = i % P; int icb = (i/P)*8;
      int x = p % IW; int t1 = p/IW; int j = t1 % SR; int nl = t1/SR;
      int gr = W0 + j;
      bool ok = (gr>=0) && (gr<IH);
      const float* src = in + ((size_t)(nimg0+nl)*IC + icb)*S + gr*IW + x;
      unsigned short hh[8];
      #pragma unroll
      for(int e=0;e<8;e++){
        float v = ok ? src[(size_t)e*S] : 0.f;
        if(BNIN) v = lrelu(fmaf(v, sc[icb+e], sh[icb+e]));
        hh[e] = f16bits(v);
      }
      *(uint4*)&linH[p*ICp + icb] = *(uint4*)hh;
    }
  }
  // prefetch B tile for ks=0
  breg0 = pf_base[0]; breg1 = pf_base[1];

  const int lane = tid & 63, wvi = tid>>6;
  const int wm = wvi>>1, wn = wvi&1;
  const int l15 = lane & 15, lh = lane>>4;

  int mxA[AM], mylA[AM], nlA[AM];
  #pragma unroll
  for(int a=0;a<AM;a++){
    int r = wm*(BM/2) + a*16 + l15;
    mxA[a] = r % IW; int t = r/IW; mylA[a] = t % RB; nlA[a] = t/RB;
  }

  f32x4 acc[AM][4] = {};

  for(int ks=0; ks<NK; ++ks){
    __syncthreads();
    // write prefetched B tile [128 n][32 k]
    *(uint4*)&bt[pf_n*32 + pf_h*16    ] = breg0;
    *(uint4*)&bt[pf_n*32 + pf_h*16 + 8] = breg1;
    __syncthreads();
    // prefetch next tile during compute
    if(ks+1 < NK){
      breg0 = pf_base[(ks+1)*4];
      breg1 = pf_base[(ks+1)*4 + 1];
    }

    int k0 = ks*32;
    int dd = k0 / IC; int icb = k0 - dd*IC;
    int dy3 = dd/3, dx3 = dd - 3*dy3;

    half8v Af[AM], Bf[4];
    #pragma unroll
    for(int a=0;a<AM;a++){
      int gx = mxA[a] - 1 + dx3;
      bool vx = (gx>=0) && (gx<IW);
      int gxc = gx<0 ? 0 : (gx>IW-1 ? IW-1 : gx);
      int jyc; bool vy;
      if(SR==IH){
        int jy = mylA[a] - 1 + dy3;
        vy = (jy>=0) && (jy<IH);
        jyc = jy<0 ? 0 : (jy>SR-1 ? SR-1 : jy);
      } else {
        jyc = mylA[a] + dy3; vy = true;   // halo rows staged (zero-filled OOB)
      }
      int p = (nlA[a]*SR + jyc)*IW + gxc;
      half8v f = *(const half8v*)&linH[p*ICp + icb + lh*8];
      if(!(vx&&vy)){
        #pragma unroll
        for(int e=0;e<8;e++) f[e] = (_Float16)0.f;
      }
      Af[a] = f;
    }
    #pragma unroll
    for(int b=0;b<4;b++)
      Bf[b] = *(const half8v*)&bt[(wn*64 + b*16 + l15)*32 + lh*8];

    #pragma unroll
    for(int a=0;a<AM;a++)
      #pragma unroll
      for(int b=0;b<4;b++)
        acc[a][b] = __builtin_amdgcn_mfma_f32_16x16x32_f16(Af[a], Bf[b], acc[a][b], 0, 0, 0);
  }

  // ---- epilogue: parity scatter store + per-oc stats
  float sb[4] = {0,0,0,0}, qb[4] = {0,0,0,0};
  #pragma unroll
  for(int b=0;b<4;b++){
    int nidx = bn0 + wn*64 + b*16 + l15;
    int oc = nidx>>2, py = (nidx>>1)&1, px = nidx&1;
    #pragma unroll
    for(int a=0;a<AM;a++){
      f32x4 c = acc[a][b];
      #pragma unroll
      for(int r=0;r<4;r++){
        int rr = wm*(BM/2) + a*16 + lh*4 + r;
        int mx = rr % IW; int t = rr/IW; int myl = t % RB; int nl = t/RB;
        int myg = (SR==IH) ? myl : (rg*RB + myl);
        float v = c[r];
        out[((size_t)(nimg0+nl)*OC + oc)*S4 + (size_t)(2*myg+py)*OW + (2*mx+px)] = v;
        sb[b] += v; qb[b] = fmaf(v,v,qb[b]);
      }
    }
  }
  #pragma unroll
  for(int b=0;b<4;b++){
    float s_ = sb[b], q_ = qb[b];
    s_ += __shfl_xor(s_,1);  q_ += __shfl_xor(q_,1);
    s_ += __shfl_xor(s_,2);  q_ += __shfl_xor(q_,2);
    s_ += __shfl_xor(s_,16); q_ += __shfl_xor(q_,16);
    s_ += __shfl_xor(s_,32); q_ += __shfl_xor(q_,32);
    if(lane < 16 && (lane&3)==0){
      int oc = (bn0 + wn*64 + b*16 + l15)>>2;
      atomicAdd(&ssum[oc], s_); atomicAdd(&ssq[oc], q_);
    }
  }
}

// in-place BN(training stats) + leaky (R3-proven). x layout (N, OC, SP)
template<int OC, int SP>
__global__ void k_bn(float* __restrict__ x, const float* __restrict__ ssum,
                     const float* __restrict__ ssq, const float* __restrict__ g,
                     const float* __restrict__ be, int n4){
  int i = blockIdx.x*256 + threadIdx.x;
  if(i >= n4) return;
  int c = ((i*4)/SP) % OC;
  const float inv_cnt = 1.f/(640.f*SP);
  float m = ssum[c]*inv_cnt;
  float var = ssq[c]*inv_cnt - m*m;
  float sc = g[c]*rsqrtf(var + 1e-5f);
  float sh = be[c] - m*sc;
  float4 xv = ((float4*)x)[i];
  xv.x = lrelu(fmaf(xv.x, sc, sh));
  xv.y = lrelu(fmaf(xv.y, sc, sh));
  xv.z = lrelu(fmaf(xv.z, sc, sh));
  xv.w = lrelu(fmaf(xv.w, sc, sh));
  ((float4*)x)[i] = xv;
}

// ---------------------------------------------------------------------------
// final ConvTranspose (32->1) + sigmoid (R3-proven; reads post-BN conv2).
__global__ __launch_bounds__(256,3) void k_final(const float* __restrict__ in,
    const float* __restrict__ w, float* __restrict__ dout, const float* __restrict__ fb){
  constexpr int IC = 32, IH = 32, IW = 32, OW = 64, RB = 8, SR = RB+2;
  __shared__ float lin[IC*SR*IW];
  __shared__ __align__(16) float lw[IC*16];

  int rg = blockIdx.x;
  int n = blockIdx.y;
  int tid = threadIdx.x;

  {
    const float4* src = (const float4*)in;
    float4* dst = (float4*)lin;
    constexpr int NV4 = IC*SR*IW/4;
    #pragma unroll
    for(int i=0;i<NV4/256;i++){
      int idx = tid + i*256;
      int ic = idx/(SR*8); int rem = idx - ic*(SR*8);
      int j = rem/8; int c4 = rem - j*8;
      int gr = RB*rg - 1 + j;
      gr = gr < 0 ? 0 : (gr > IH-1 ? IH-1 : gr);
      dst[idx] = src[((size_t)(n*IC+ic)*IH + gr)*8 + c4];
    }
    if(tid < 128) ((float4*)lw)[tid] = ((const float4*)w)[tid];
  }
  float fbv = fb[0];
  __syncthreads();

  int tl = tid / IW, tx = tid % IW;
  int ty = RB*rg + tl;

  int offs[3][3]; float msk[3][3];
  #pragma unroll
  for(int dy=0;dy<3;dy++){
    int iy = ty-1+dy; bool vy = (iy>=0)&&(iy<IH);
    #pragma unroll
    for(int dx=0;dx<3;dx++){
      int ix = tx-1+dx; bool vx = (ix>=0)&&(ix<IW);
      int lcol = ix < 0 ? 0 : (ix > IW-1 ? IW-1 : ix);
      offs[dy][dx] = (tl+dy)*IW + lcol;
      msk[dy][dx]  = (vy&&vx) ? 1.f : 0.f;
    }
  }

  float acc[2][2] = {{0.f,0.f},{0.f,0.f}};
  #pragma unroll 4
  for(int ic=0; ic<IC; ic++){
    const float* p = lin + ic*(SR*IW);
    float v[3][3];
    #pragma unroll
    for(int dy=0;dy<3;dy++)
      #pragma unroll
      for(int dx=0;dx<3;dx++)
        v[dy][dx] = p[offs[dy][dx]] * msk[dy][dx];
    const float4* wr = (const float4*)(lw + ic*16);
    float4 w0=wr[0], w1=wr[1], w2=wr[2], w3=wr[3];
    float wv[16] = {w0.x,w0.y,w0.z,w0.w, w1.x,w1.y,w1.z,w1.w,
                    w2.x,w2.y,w2.z,w2.w, w3.x,w3.y,w3.z,w3.w};
    #pragma unroll
    for(int r=0;r<2;r++)
      #pragma unroll
      for(int s2=0;s2<2;s2++)
        #pragma unroll
        for(int a=0;a<2;a++)
          #pragma unroll
          for(int b2=0;b2<2;b2++)
            acc[r][s2] = fmaf(v[a+r][b2+s2], wv[(3-2*a-r)*4 + (3-2*b2-s2)], acc[r][s2]);
  }

  float* ob = dout + (size_t)n*OW*OW;
  #pragma unroll
  for(int r=0;r<2;r++)
    #pragma unroll
    for(int s2=0;s2<2;s2++){
      float vv = acc[r][s2] + fbv;
      ob[(2*ty+r)*OW + (2*tx+s2)] = 1.f/(1.f+__expf(-vv));
    }
}

extern "C" void kernel_launch(void* const* d_in, const int* in_sizes, int n_in,
                              void* d_out, int out_size, void* d_ws, size_t ws_size,
                              hipStream_t stream){
  const float* z       = (const float*)d_in[0];
  const float* fhw     = (const float*)d_in[1];
  const float* fhb     = (const float*)d_in[2];
  const float* fcw     = (const float*)d_in[3];
  const float* fcb     = (const float*)d_in[4];
  const float* wih     = (const float*)d_in[5];
  const float* bih     = (const float*)d_in[6];
  const float* whh     = (const float*)d_in[7];
  const float* bhh     = (const float*)d_in[8];
  const float* init_inp= (const float*)d_in[9];
  const float* fow     = (const float*)d_in[10];
  const float* fob     = (const float*)d_in[11];
  const float* cfw     = (const float*)d_in[12];
  const float* cfb     = (const float*)d_in[13];
  const float* dw0     = (const float*)d_in[14];
  const float* g0      = (const float*)d_in[15];
  const float* be0     = (const float*)d_in[16];
  const float* dw1     = (const float*)d_in[17];
  const float* g1      = (const float*)d_in[18];
  const float* be1     = (const float*)d_in[19];
  const float* dw2     = (const float*)d_in[20];
  const float* g2      = (const float*)d_in[21];
  const float* be2     = (const float*)d_in[22];
  const float* fw      = (const float*)d_in[23];
  const float* fb      = (const float*)d_in[24];

  float* ws    = (float*)d_ws;
  float* conv2 = ws;                 // 640*32*1024 = 20971520 floats
  float* conv1 = ws + 20971520;      // 640*64*256  = 10485760
  float* conv0 = ws + 31457280;      // 640*128*64  =  5242880
  float* fc1   = ws + 36700160;      // 640*4096    =  2621440
  float* feats = ws + 39321600;      // 640*512     =   327680
  float* outs  = ws + 39649280;      // 20*32*256   =   163840
  float* Wc    = ws + 39813120;      // 1024*256    =   262144
  float* bias0 = ws + 40075264;      // 1024
  float* bias1 = ws + 40076288;      // 1024
  float* h0    = ws + 40077312;      // 8192
  float* cbuf  = ws + 40085504;      // 8192
  float* stats = ws + 40093696;      // 448
  float* sum0 = stats,     *sq0 = stats+128;
  float* sum1 = stats+256, *sq1 = stats+320;
  float* sum2 = stats+384, *sq2 = stats+416;

  // transformed weights live in regions dead at their use time:
  //  Wz0/Wz1 in conv2 (dead before L2 writes conv2); Wz2 in feats (dead after k_cnnfc)
  unsigned short* Wz0 = (unsigned short*)conv2;                 // 512*2304 f16
  unsigned short* Wz1 = (unsigned short*)(conv2 + 600000);      // 256*1152 f16
  unsigned short* Wz2 = (unsigned short*)feats;                 // 128*576 f16

  hipLaunchKernelGGL(k_wc,    dim3(256), dim3(256), 0, stream, wih, whh, Wc);
  hipLaunchKernelGGL(k_bias,  dim3(4),   dim3(256), 0, stream, wih, bih, bhh, init_inp, bias0, bias1);
  hipLaunchKernelGGL(k_rowfc, dim3(32),  dim3(256), 0, stream, z, fhw, fhb, h0);
  hipLaunchKernelGGL(k_rowfc, dim3(32),  dim3(256), 0, stream, z, fcw, fcb, cbuf);
  hipLaunchKernelGGL(k_zero,  dim3(2),   dim3(256), 0, stream, stats, 448);

  for(int t=0;t<T_;t++){
    const float* W  = (t==0) ? whh   : Wc;
    const float* bs = (t==0) ? bias0 : bias1;
    const float* hp = (t==0) ? h0    : outs + (t-1)*B_*H_;
    hipLaunchKernelGGL(k_lstm, dim3(4,32), dim3(256), 0, stream, hp, cbuf, W, bs, outs + t*B_*H_);
  }

  hipLaunchKernelGGL(k_fcout, dim3(2,NT_), dim3(256), 0, stream, outs, fow, fob, feats);
  hipLaunchKernelGGL(k_cnnfc, dim3(4,80),  dim3(256), 0, stream, feats, cfw, cfb, fc1);

  hipLaunchKernelGGL((k_wz<256,128>), dim3(4608), dim3(256), 0, stream, dw0, Wz0);
  hipLaunchKernelGGL((k_wz<128,64>),  dim3(1152), dim3(256), 0, stream, dw1, Wz1);
  hipLaunchKernelGGL((k_wz<64,32>),   dim3(288),  dim3(256), 0, stream, dw2, Wz2);

  // L0 (MFMA): IC=256 OC=128 IH=4, NL=4 RB=4 SR=4 BM=64, grid(160,4)
  hipLaunchKernelGGL((k_gemmdc<256,128,4,4,4,4,64,false>), dim3(160,4), dim3(256), 0, stream,
                     fc1, Wz0, conv0, (const float*)nullptr, (const float*)nullptr, sum0, sq0);
  hipLaunchKernelGGL((k_bn<128,64>),   dim3(5120),  dim3(256), 0, stream, conv0, sum0, sq0, g0, be0, 1310720);

  // L1 (MFMA): IC=128 OC=64 IH=8, NL=2 RB=8 SR=8 BM=128, grid(320,2)
  hipLaunchKernelGGL((k_gemmdc<128,64,8,2,8,8,128,false>), dim3(320,2), dim3(256), 0, stream,
                     conv0, Wz1, conv1, (const float*)nullptr, (const float*)nullptr, sum1, sq1);
  hipLaunchKernelGGL((k_bn<64,256>),   dim3(10240), dim3(256), 0, stream, conv1, sum1, sq1, g1, be1, 2621440);

  // L2 (MFMA): IC=64 OC=32 IH=16, NL=1 RB=8 SR=10 BM=128, grid(1280,1)
  hipLaunchKernelGGL((k_gemmdc<64,32,16,1,8,10,128,false>), dim3(1280,1), dim3(256), 0, stream,
                     conv1, Wz2, conv2, (const float*)nullptr, (const float*)nullptr, sum2, sq2);
  hipLaunchKernelGGL((k_bn<32,1024>),  dim3(20480), dim3(256), 0, stream, conv2, sum2, sq2, g2, be2, 5242880);

  // final (R3-proven)
  hipLaunchKernelGGL(k_final, dim3(4,640), dim3(256), 0, stream, conv2, fw, (float*)d_out, fb);
}

// Round 10
// 689.538 us; speedup vs baseline: 4.2858x; 1.4713x over previous
//
#include <hip/hip_runtime.h>
#include <math.h>

#define B_ 32
#define T_ 20
#define H_ 256
#define F_ 512
#define NT_ 640

typedef __attribute__((ext_vector_type(8))) _Float16 half8v;
typedef __attribute__((ext_vector_type(4))) float f32x4;

__device__ __forceinline__ float sigf(float x){ return 1.f/(1.f+__expf(-x)); }
__device__ __forceinline__ float lrelu(float x){ return x>0.f ? x : 0.2f*x; }
__device__ __forceinline__ float dot4(float4 a, float4 b){
  return fmaf(a.x,b.x, fmaf(a.y,b.y, fmaf(a.z,b.z, a.w*b.w)));
}
__device__ __forceinline__ unsigned short f16bits(float x){
  _Float16 h = (_Float16)x;                 // RNE
  union { _Float16 h; unsigned short u; } cv; cv.h = h; return cv.u;
}

// Wc = w_ih + w_hh
__global__ void k_wc(const float* __restrict__ wih, const float* __restrict__ whh,
                     float* __restrict__ Wc){
  int i = blockIdx.x*256 + threadIdx.x;
  float4 a = ((const float4*)wih)[i];
  float4 b = ((const float4*)whh)[i];
  ((float4*)Wc)[i] = make_float4(a.x+b.x, a.y+b.y, a.z+b.z, a.w+b.w);
}

// bias1 = b_ih + b_hh ; bias0 = init_inp @ w_ih.T + bias1
__global__ void k_bias(const float* __restrict__ wih, const float* __restrict__ bih,
                       const float* __restrict__ bhh, const float* __restrict__ init_inp,
                       float* __restrict__ bias0, float* __restrict__ bias1){
  __shared__ __align__(16) float xs[H_];
  int tid = threadIdx.x;
  xs[tid] = init_inp[tid];
  __syncthreads();
  int j = blockIdx.x*256 + tid;
  const float4* wr = (const float4*)(wih + (size_t)j*H_);
  const float4* xx = (const float4*)xs;
  float acc = 0.f;
  #pragma unroll 8
  for(int k=0;k<H_/4;k++) acc += dot4(wr[k], xx[k]);
  float b1 = bih[j] + bhh[j];
  bias1[j] = b1;
  bias0[j] = acc + b1;
}

// out[b][j] = z[b] . W[j] + bias[j]
__global__ void k_rowfc(const float* __restrict__ z, const float* __restrict__ W,
                        const float* __restrict__ bias, float* __restrict__ out){
  __shared__ __align__(16) float zs[H_];
  int b = blockIdx.x, j = threadIdx.x;
  zs[j] = z[b*H_ + j];
  __syncthreads();
  const float4* wr = (const float4*)(W + (size_t)j*H_);
  const float4* zz = (const float4*)zs;
  float acc = bias[j];
  #pragma unroll 8
  for(int k=0;k<H_/4;k++) acc += dot4(wr[k], zz[k]);
  out[b*H_+j] = acc;
}

// one LSTM step
__global__ void k_lstm(const float* __restrict__ hprev, float* __restrict__ c,
                       const float* __restrict__ W, const float* __restrict__ bias,
                       float* __restrict__ hout){
  __shared__ __align__(16) float hs[H_];
  __shared__ float gs[4][64];
  int b = blockIdx.y, jg = blockIdx.x, tid = threadIdx.x;
  hs[tid] = hprev[b*H_ + tid];
  __syncthreads();
  int g = tid>>6, jj = tid&63;
  int row = g*H_ + jg*64 + jj;
  const float4* wr = (const float4*)(W + (size_t)row*H_);
  const float4* hh = (const float4*)hs;
  float acc = bias[row];
  #pragma unroll 8
  for(int k=0;k<H_/4;k++) acc += dot4(wr[k], hh[k]);
  gs[g][jj] = acc;
  __syncthreads();
  if(tid < 64){
    int j = jg*64 + tid;
    float iv = gs[0][tid], fv = gs[1][tid], gv = gs[2][tid], ov = gs[3][tid];
    int ci = b*H_ + j;
    float cn = sigf(fv)*c[ci] + sigf(iv)*tanhf(gv);
    c[ci] = cn;
    hout[b*H_ + j] = sigf(ov)*tanhf(cn);
  }
}

// feats[n][f] = leaky(outs[t][b] . w[f] + bias[f]),  n = b*T+t
__global__ void k_fcout(const float* __restrict__ outs, const float* __restrict__ w,
                        const float* __restrict__ bias, float* __restrict__ feats){
  __shared__ __align__(16) float hs[H_];
  int n = blockIdx.y; int b = n/T_, t = n - b*T_;
  int tid = threadIdx.x;
  hs[tid] = outs[(t*B_ + b)*H_ + tid];
  __syncthreads();
  int f = blockIdx.x*256 + tid;
  const float4* wr = (const float4*)(w + (size_t)f*H_);
  const float4* hh = (const float4*)hs;
  float acc = bias[f];
  #pragma unroll 8
  for(int k=0;k<H_/4;k++) acc += dot4(wr[k], hh[k]);
  feats[n*F_ + f] = lrelu(acc);
}

// fc1[n][oc] = leaky(feats[n] . w[oc] + b[oc])
__global__ __launch_bounds__(256) void k_cnnfc(const float* __restrict__ feats,
    const float* __restrict__ w, const float* __restrict__ bias, float* __restrict__ out){
  __shared__ __align__(16) float fe[8*F_];
  int ocg = blockIdx.x, ng = blockIdx.y, tid = threadIdx.x;
  const float4* src = (const float4*)(feats + (size_t)ng*8*F_);
  float4* dst = (float4*)fe;
  for(int i=tid;i<8*F_/4;i+=256) dst[i] = src[i];
  __syncthreads();
  int oc0 = ocg*1024 + tid;
  const float4* w0 = (const float4*)(w + (size_t)(oc0      )*F_);
  const float4* w1 = (const float4*)(w + (size_t)(oc0+256 )*F_);
  const float4* w2 = (const float4*)(w + (size_t)(oc0+512 )*F_);
  const float4* w3 = (const float4*)(w + (size_t)(oc0+768 )*F_);
  float acc[4][8];
  #pragma unroll
  for(int i=0;i<4;i++){
    float bv = bias[oc0 + i*256];
    #pragma unroll
    for(int nn=0;nn<8;nn++) acc[i][nn]=bv;
  }
  for(int k=0;k<F_/4;k++){
    float4 wv0=w0[k], wv1=w1[k], wv2=w2[k], wv3=w3[k];
    #pragma unroll
    for(int nn=0;nn<8;nn++){
      float4 f = ((const float4*)(fe + nn*F_))[k];
      acc[0][nn] += dot4(wv0,f);
      acc[1][nn] += dot4(wv1,f);
      acc[2][nn] += dot4(wv2,f);
      acc[3][nn] += dot4(wv3,f);
    }
  }
  #pragma unroll
  for(int i=0;i<4;i++)
    #pragma unroll
    for(int nn=0;nn<8;nn++)
      out[(size_t)(ng*8+nn)*4096 + ocg*1024 + i*256 + tid] = lrelu(acc[i][nn]);
}

// ---------------------------------------------------------------------------
// weight transform: Wz[n=(oc*4+py*2+px)][k=(dy3*3+dx3)*IC+ic] (fp16, k-fastest)
template<int IC, int OC>
__global__ void k_wz(const float* __restrict__ w, unsigned short* __restrict__ Wz){
  constexpr int K9 = 9*IC, N4 = 4*OC;
  int i = blockIdx.x*256 + threadIdx.x;
  if(i >= N4*K9) return;
  int n = i / K9; int k = i - n*K9;
  int oc = n>>2, py = (n>>1)&1, px = n&1;
  int dd = k / IC; int ic = k - dd*IC;
  int dy3 = dd/3, dx3 = dd - 3*dy3;
  int ky = py + 3 - 2*dy3, kx = px + 3 - 2*dx3;
  float v = 0.f;
  if(ky>=0 && ky<4 && kx>=0 && kx<4)
    v = w[(((size_t)ic*OC + oc)*4 + ky)*4 + kx];
  Wz[i] = f16bits(v);
}

// ---------------------------------------------------------------------------
// MFMA implicit-GEMM deconv, fp16 operands, fp32 accum. OPERAND-SWAPPED:
// acc = mfma(Bf, Af, acc) so C cols (l15) = M (coalesced stores) and
// C rows (lh,r) = N (oc wave-uniform per lane-group -> cheap stats).
// Stats: per-(oc,block,wm) float2 partials to scratch (no global atomics).
template<int IC, int OC, int IH, int NL, int RB, int SR, int BM, bool BNIN>
__global__ __launch_bounds__(256) void k_gemmdc(
    const float* __restrict__ in, const unsigned short* __restrict__ Wz,
    float* __restrict__ out, const float* __restrict__ sc, const float* __restrict__ sh,
    float2* __restrict__ scr, int CB)
{
  constexpr int IW = IH, OW = 2*IH;
  constexpr int S  = IH*IW, S4 = 4*S;
  constexpr int K9 = 9*IC;
  constexpr int ICp = IC + 8;
  constexpr int TS = IH/RB;
  constexpr int P  = NL*SR*IW;
  constexpr int NK = K9/32;
  constexpr int BN = 128;
  constexpr int AM = BM/32;
  static_assert(NL*RB*IW == BM, "BM mismatch");

  __shared__ unsigned short linH[P*ICp];
  __shared__ unsigned short bt[BN*32];

  const int tid = threadIdx.x;
  const int bm = blockIdx.x, bn0 = blockIdx.y*BN;
  const int nimg0 = (bm/TS)*NL;
  const int rg = bm % TS;
  const int W0 = (SR==IH) ? 0 : (rg*RB - 1);

  // B prefetch addressing: thread covers (n = tid>>1, half h = tid&1 -> 16 k)
  const int pf_n = tid>>1, pf_h = tid&1;
  const uint4* pf_base = (const uint4*)(Wz + (size_t)(bn0+pf_n)*K9 + pf_h*16);
  uint4 breg0, breg1;

  // ---- stage A slab (fp16 channel-last), fused BN+leaky if BNIN
  {
    constexpr int NIT = P*(IC/8)/256;
    #pragma unroll
    for(int it=0; it<NIT; ++it){
      int i = tid + it*256;
      int p = i % P; int icb = (i/P)*8;
      int x = p % IW; int t1 = p/IW; int j = t1 % SR; int nl = t1/SR;
      int gr = W0 + j;
      bool ok = (gr>=0) && (gr<IH);
      const float* src = in + ((size_t)(nimg0+nl)*IC + icb)*S + gr*IW + x;
      unsigned short hh[8];
      #pragma unroll
      for(int e=0;e<8;e++){
        float v = ok ? src[(size_t)e*S] : 0.f;
        if(BNIN) v = lrelu(fmaf(v, sc[icb+e], sh[icb+e]));
        hh[e] = f16bits(v);
      }
      *(uint4*)&linH[p*ICp + icb] = *(uint4*)hh;
    }
  }
  // prefetch B tile for ks=0
  breg0 = pf_base[0]; breg1 = pf_base[1];

  const int lane = tid & 63, wvi = tid>>6;
  const int wm = wvi>>1, wn = wvi&1;
  const int l15 = lane & 15, lh = lane>>4;

  int mxA[AM], mylA[AM], nlA[AM];
  #pragma unroll
  for(int a=0;a<AM;a++){
    int r = wm*(BM/2) + a*16 + l15;
    mxA[a] = r % IW; int t = r/IW; mylA[a] = t % RB; nlA[a] = t/RB;
  }

  f32x4 acc[AM][4] = {};

  for(int ks=0; ks<NK; ++ks){
    __syncthreads();
    // write prefetched B tile [128 n][32 k]
    *(uint4*)&bt[pf_n*32 + pf_h*16    ] = breg0;
    *(uint4*)&bt[pf_n*32 + pf_h*16 + 8] = breg1;
    __syncthreads();
    // prefetch next tile during compute
    if(ks+1 < NK){
      breg0 = pf_base[(ks+1)*4];
      breg1 = pf_base[(ks+1)*4 + 1];
    }

    int k0 = ks*32;
    int dd = k0 / IC; int icb = k0 - dd*IC;
    int dy3 = dd/3, dx3 = dd - 3*dy3;

    half8v Af[AM], Bf[4];
    #pragma unroll
    for(int a=0;a<AM;a++){
      int gx = mxA[a] - 1 + dx3;
      bool vx = (gx>=0) && (gx<IW);
      int gxc = gx<0 ? 0 : (gx>IW-1 ? IW-1 : gx);
      int jyc; bool vy;
      if(SR==IH){
        int jy = mylA[a] - 1 + dy3;
        vy = (jy>=0) && (jy<IH);
        jyc = jy<0 ? 0 : (jy>SR-1 ? SR-1 : jy);
      } else {
        jyc = mylA[a] + dy3; vy = true;   // halo rows staged (zero-filled OOB)
      }
      int p = (nlA[a]*SR + jyc)*IW + gxc;
      half8v f = *(const half8v*)&linH[p*ICp + icb + lh*8];
      if(!(vx&&vy)){
        #pragma unroll
        for(int e=0;e<8;e++) f[e] = (_Float16)0.f;
      }
      Af[a] = f;
    }
    #pragma unroll
    for(int b=0;b<4;b++)
      Bf[b] = *(const half8v*)&bt[(wn*64 + b*16 + l15)*32 + lh*8];

    // OPERAND SWAP: rows(lh,r)=N, cols(l15)=M
    #pragma unroll
    for(int a=0;a<AM;a++)
      #pragma unroll
      for(int b=0;b<4;b++)
        acc[a][b] = __builtin_amdgcn_mfma_f32_16x16x32_f16(Bf[b], Af[a], acc[a][b], 0, 0, 0);
  }

  // ---- epilogue: coalesced stores (l15 -> mx) + scratch stats
  #pragma unroll
  for(int b=0;b<4;b++){
    float s_ = 0.f, q_ = 0.f;
    int Nbase = bn0 + wn*64 + b*16 + lh*4;
    #pragma unroll
    for(int r=0;r<4;r++){
      int N = Nbase + r;
      int oc = N>>2, py = (N>>1)&1, px = N&1;
      #pragma unroll
      for(int a=0;a<AM;a++){
        float v = acc[a][b][r];
        int myg = (SR==IH) ? mylA[a] : (rg*RB + mylA[a]);
        out[((size_t)(nimg0+nlA[a])*OC + oc)*S4 + (size_t)(2*myg+py)*OW + (2*mxA[a]+px)] = v;
        s_ += v; q_ = fmaf(v,v,q_);
      }
    }
    // reduce over the 16 M-lanes (l15)
    s_ += __shfl_xor(s_,1); q_ += __shfl_xor(q_,1);
    s_ += __shfl_xor(s_,2); q_ += __shfl_xor(q_,2);
    s_ += __shfl_xor(s_,4); q_ += __shfl_xor(q_,4);
    s_ += __shfl_xor(s_,8); q_ += __shfl_xor(q_,8);
    if(l15 == 0){
      int oc = ((bn0 + wn*64 + b*16)>>2) + lh;
      scr[(size_t)oc*CB + bm*2 + wm] = make_float2(s_, q_);
    }
  }
}

// reduce per-block float2 partials -> sum/sq per oc. grid(OC), block 256.
__global__ void k_bnred(const float2* __restrict__ scr, float* __restrict__ sum,
                        float* __restrict__ sq, int CB){
  int oc = blockIdx.x, tid = threadIdx.x;
  float s = 0.f, q = 0.f;
  for(int i = tid; i < CB; i += 256){
    float2 v = scr[(size_t)oc*CB + i];
    s += v.x; q += v.y;
  }
  #pragma unroll
  for(int m=1;m<64;m<<=1){ s += __shfl_xor(s,m); q += __shfl_xor(q,m); }
  __shared__ float ls[4], lq[4];
  int w = tid>>6;
  if((tid&63)==0){ ls[w]=s; lq[w]=q; }
  __syncthreads();
  if(tid==0){
    sum[oc] = ls[0]+ls[1]+ls[2]+ls[3];
    sq[oc]  = lq[0]+lq[1]+lq[2]+lq[3];
  }
}

// in-place BN(training stats) + leaky. x layout (N, OC, SP)
template<int OC, int SP>
__global__ void k_bn(float* __restrict__ x, const float* __restrict__ ssum,
                     const float* __restrict__ ssq, const float* __restrict__ g,
                     const float* __restrict__ be, int n4){
  int i = blockIdx.x*256 + threadIdx.x;
  if(i >= n4) return;
  int c = ((i*4)/SP) % OC;
  const float inv_cnt = 1.f/(640.f*SP);
  float m = ssum[c]*inv_cnt;
  float var = ssq[c]*inv_cnt - m*m;
  float sc = g[c]*rsqrtf(var + 1e-5f);
  float sh = be[c] - m*sc;
  float4 xv = ((float4*)x)[i];
  xv.x = lrelu(fmaf(xv.x, sc, sh));
  xv.y = lrelu(fmaf(xv.y, sc, sh));
  xv.z = lrelu(fmaf(xv.z, sc, sh));
  xv.w = lrelu(fmaf(xv.w, sc, sh));
  ((float4*)x)[i] = xv;
}

// ---------------------------------------------------------------------------
// final ConvTranspose (32->1) + sigmoid (reads post-BN conv2).
__global__ __launch_bounds__(256,3) void k_final(const float* __restrict__ in,
    const float* __restrict__ w, float* __restrict__ dout, const float* __restrict__ fb){
  constexpr int IC = 32, IH = 32, IW = 32, OW = 64, RB = 8, SR = RB+2;
  __shared__ float lin[IC*SR*IW];
  __shared__ __align__(16) float lw[IC*16];

  int rg = blockIdx.x;
  int n = blockIdx.y;
  int tid = threadIdx.x;

  {
    const float4* src = (const float4*)in;
    float4* dst = (float4*)lin;
    constexpr int NV4 = IC*SR*IW/4;
    #pragma unroll
    for(int i=0;i<NV4/256;i++){
      int idx = tid + i*256;
      int ic = idx/(SR*8); int rem = idx - ic*(SR*8);
      int j = rem/8; int c4 = rem - j*8;
      int gr = RB*rg - 1 + j;
      gr = gr < 0 ? 0 : (gr > IH-1 ? IH-1 : gr);
      dst[idx] = src[((size_t)(n*IC+ic)*IH + gr)*8 + c4];
    }
    if(tid < 128) ((float4*)lw)[tid] = ((const float4*)w)[tid];
  }
  float fbv = fb[0];
  __syncthreads();

  int tl = tid / IW, tx = tid % IW;
  int ty = RB*rg + tl;

  int offs[3][3]; float msk[3][3];
  #pragma unroll
  for(int dy=0;dy<3;dy++){
    int iy = ty-1+dy; bool vy = (iy>=0)&&(iy<IH);
    #pragma unroll
    for(int dx=0;dx<3;dx++){
      int ix = tx-1+dx; bool vx = (ix>=0)&&(ix<IW);
      int lcol = ix < 0 ? 0 : (ix > IW-1 ? IW-1 : ix);
      offs[dy][dx] = (tl+dy)*IW + lcol;
      msk[dy][dx]  = (vy&&vx) ? 1.f : 0.f;
    }
  }

  float acc[2][2] = {{0.f,0.f},{0.f,0.f}};
  #pragma unroll 4
  for(int ic=0; ic<IC; ic++){
    const float* p = lin + ic*(SR*IW);
    float v[3][3];
    #pragma unroll
    for(int dy=0;dy<3;dy++)
      #pragma unroll
      for(int dx=0;dx<3;dx++)
        v[dy][dx] = p[offs[dy][dx]] * msk[dy][dx];
    const float4* wr = (const float4*)(lw + ic*16);
    float4 w0=wr[0], w1=wr[1], w2=wr[2], w3=wr[3];
    float wv[16] = {w0.x,w0.y,w0.z,w0.w, w1.x,w1.y,w1.z,w1.w,
                    w2.x,w2.y,w2.z,w2.w, w3.x,w3.y,w3.z,w3.w};
    #pragma unroll
    for(int r=0;r<2;r++)
      #pragma unroll
      for(int s2=0;s2<2;s2++)
        #pragma unroll
        for(int a=0;a<2;a++)
          #pragma unroll
          for(int b2=0;b2<2;b2++)
            acc[r][s2] = fmaf(v[a+r][b2+s2], wv[(3-2*a-r)*4 + (3-2*b2-s2)], acc[r][s2]);
  }

  float* ob = dout + (size_t)n*OW*OW;
  #pragma unroll
  for(int r=0;r<2;r++)
    #pragma unroll
    for(int s2=0;s2<2;s2++){
      float vv = acc[r][s2] + fbv;
      ob[(2*ty+r)*OW + (2*tx+s2)] = 1.f/(1.f+__expf(-vv));
    }
}

extern "C" void kernel_launch(void* const* d_in, const int* in_sizes, int n_in,
                              void* d_out, int out_size, void* d_ws, size_t ws_size,
                              hipStream_t stream){
  const float* z       = (const float*)d_in[0];
  const float* fhw     = (const float*)d_in[1];
  const float* fhb     = (const float*)d_in[2];
  const float* fcw     = (const float*)d_in[3];
  const float* fcb     = (const float*)d_in[4];
  const float* wih     = (const float*)d_in[5];
  const float* bih     = (const float*)d_in[6];
  const float* whh     = (const float*)d_in[7];
  const float* bhh     = (const float*)d_in[8];
  const float* init_inp= (const float*)d_in[9];
  const float* fow     = (const float*)d_in[10];
  const float* fob     = (const float*)d_in[11];
  const float* cfw     = (const float*)d_in[12];
  const float* cfb     = (const float*)d_in[13];
  const float* dw0     = (const float*)d_in[14];
  const float* g0      = (const float*)d_in[15];
  const float* be0     = (const float*)d_in[16];
  const float* dw1     = (const float*)d_in[17];
  const float* g1      = (const float*)d_in[18];
  const float* be1     = (const float*)d_in[19];
  const float* dw2     = (const float*)d_in[20];
  const float* g2      = (const float*)d_in[21];
  const float* be2     = (const float*)d_in[22];
  const float* fw      = (const float*)d_in[23];
  const float* fb      = (const float*)d_in[24];

  float* ws    = (float*)d_ws;
  float* conv2 = ws;                 // 640*32*1024 = 20971520 floats
  float* conv1 = ws + 20971520;      // 640*64*256  = 10485760
  float* conv0 = ws + 31457280;      // 640*128*64  =  5242880
  float* fc1   = ws + 36700160;      // 640*4096    =  2621440
  float* feats = ws + 39321600;      // 640*512     =   327680
  float* outs  = ws + 39649280;      // 20*32*256   =   163840
  float* Wc    = ws + 39813120;      // 1024*256    =   262144
  float* bias0 = ws + 40075264;      // 1024
  float* bias1 = ws + 40076288;      // 1024
  float* h0    = ws + 40077312;      // 8192
  float* cbuf  = ws + 40085504;      // 8192
  float* stats = ws + 40093696;      // 448
  float* sum0 = stats,     *sq0 = stats+128;
  float* sum1 = stats+256, *sq1 = stats+320;
  float* sum2 = stats+384, *sq2 = stats+416;

  // transformed weights + stats scratch live in regions dead at use time:
  //  Wz0/Wz1 in conv2 (dead before L2 writes conv2); Wz2 in feats[0..36864]
  //  scr0/scr1 in outs (dead after k_fcout); scr2 in feats+40960
  unsigned short* Wz0 = (unsigned short*)conv2;                 // 512*2304 f16
  unsigned short* Wz1 = (unsigned short*)(conv2 + 600000);      // 256*1152 f16
  unsigned short* Wz2 = (unsigned short*)feats;                 // 128*576 f16
  float2* scr0 = (float2*)outs;                 // 128 oc * 320 = 40960 float2
  float2* scr1 = (float2*)(outs + 81920);       // 64 oc * 640  = 40960 float2
  float2* scr2 = (float2*)(feats + 40960);      // 32 oc * 2560 = 81920 float2

  hipLaunchKernelGGL(k_wc,    dim3(256), dim3(256), 0, stream, wih, whh, Wc);
  hipLaunchKernelGGL(k_bias,  dim3(4),   dim3(256), 0, stream, wih, bih, bhh, init_inp, bias0, bias1);
  hipLaunchKernelGGL(k_rowfc, dim3(32),  dim3(256), 0, stream, z, fhw, fhb, h0);
  hipLaunchKernelGGL(k_rowfc, dim3(32),  dim3(256), 0, stream, z, fcw, fcb, cbuf);

  for(int t=0;t<T_;t++){
    const float* W  = (t==0) ? whh   : Wc;
    const float* bs = (t==0) ? bias0 : bias1;
    const float* hp = (t==0) ? h0    : outs + (t-1)*B_*H_;
    hipLaunchKernelGGL(k_lstm, dim3(4,32), dim3(256), 0, stream, hp, cbuf, W, bs, outs + t*B_*H_);
  }

  hipLaunchKernelGGL(k_fcout, dim3(2,NT_), dim3(256), 0, stream, outs, fow, fob, feats);
  hipLaunchKernelGGL(k_cnnfc, dim3(4,80),  dim3(256), 0, stream, feats, cfw, cfb, fc1);

  hipLaunchKernelGGL((k_wz<256,128>), dim3(4608), dim3(256), 0, stream, dw0, Wz0);
  hipLaunchKernelGGL((k_wz<128,64>),  dim3(1152), dim3(256), 0, stream, dw1, Wz1);
  hipLaunchKernelGGL((k_wz<64,32>),   dim3(288),  dim3(256), 0, stream, dw2, Wz2);

  // L0 (MFMA): IC=256 OC=128 IH=4, NL=4 RB=4 SR=4 BM=64, grid(160,4), CB=320
  hipLaunchKernelGGL((k_gemmdc<256,128,4,4,4,4,64,false>), dim3(160,4), dim3(256), 0, stream,
                     fc1, Wz0, conv0, (const float*)nullptr, (const float*)nullptr, scr0, 320);
  hipLaunchKernelGGL(k_bnred, dim3(128), dim3(256), 0, stream, scr0, sum0, sq0, 320);
  hipLaunchKernelGGL((k_bn<128,64>),   dim3(5120),  dim3(256), 0, stream, conv0, sum0, sq0, g0, be0, 1310720);

  // L1 (MFMA): IC=128 OC=64 IH=8, NL=2 RB=8 SR=8 BM=128, grid(320,2), CB=640
  hipLaunchKernelGGL((k_gemmdc<128,64,8,2,8,8,128,false>), dim3(320,2), dim3(256), 0, stream,
                     conv0, Wz1, conv1, (const float*)nullptr, (const float*)nullptr, scr1, 640);
  hipLaunchKernelGGL(k_bnred, dim3(64), dim3(256), 0, stream, scr1, sum1, sq1, 640);
  hipLaunchKernelGGL((k_bn<64,256>),   dim3(10240), dim3(256), 0, stream, conv1, sum1, sq1, g1, be1, 2621440);

  // L2 (MFMA): IC=64 OC=32 IH=16, NL=1 RB=8 SR=10 BM=128, grid(1280,1), CB=2560
  hipLaunchKernelGGL((k_gemmdc<64,32,16,1,8,10,128,false>), dim3(1280,1), dim3(256), 0, stream,
                     conv1, Wz2, conv2, (const float*)nullptr, (const float*)nullptr, scr2, 2560);
  hipLaunchKernelGGL(k_bnred, dim3(32), dim3(256), 0, stream, scr2, sum2, sq2, 2560);
  hipLaunchKernelGGL((k_bn<32,1024>),  dim3(20480), dim3(256), 0, stream, conv2, sum2, sq2, g2, be2, 5242880);

  // final
  hipLaunchKernelGGL(k_final, dim3(4,640), dim3(256), 0, stream, conv2, fw, (float*)d_out, fb);
}